// Round 2
// baseline (6935.902 us; speedup 1.0000x reference)
//
#include <hip/hip_runtime.h>
#include <hip/hip_bf16.h>
#include <math.h>

#define NSEQ 2048
#define ROWS 4096   // B*N
#define KNN 9

// ---------- block reduce helpers (blockDim.x == 256) ----------
__device__ __forceinline__ float blockReduceSum(float v, float* red) {
    int tid = threadIdx.x;
    red[tid] = v; __syncthreads();
    for (int s = 128; s > 0; s >>= 1) {
        if (tid < s) red[tid] += red[tid + s];
        __syncthreads();
    }
    float r = red[0]; __syncthreads();
    return r;
}

// ---------- generic GEMM: C[M,N] = A[M,K] @ W[N,K]^T + bias[N] ----------
// M,N multiples of 64; K multiple of 16. 256 threads, 64x64 tile, 4x4/thread.
__global__ __launch_bounds__(256) void gemm_bias(
        const float* __restrict__ A, const float* __restrict__ W,
        const float* __restrict__ bias, float* __restrict__ C,
        int M, int N, int K)
{
    __shared__ float As[16][65];
    __shared__ float Ws[16][65];
    int tid = threadIdx.x;
    int bm = blockIdx.y * 64, bn = blockIdx.x * 64;
    int tx = tid & 15, ty = tid >> 4;
    int lr = tid >> 2, lk = (tid & 3) << 2;
    float acc[4][4] = {};
    for (int k0 = 0; k0 < K; k0 += 16) {
        const float* Ap = A + (size_t)(bm + lr) * K + (k0 + lk);
        const float* Wp = W + (size_t)(bn + lr) * K + (k0 + lk);
        #pragma unroll
        for (int j = 0; j < 4; ++j) As[lk + j][lr] = Ap[j];
        #pragma unroll
        for (int j = 0; j < 4; ++j) Ws[lk + j][lr] = Wp[j];
        __syncthreads();
        #pragma unroll
        for (int k = 0; k < 16; ++k) {
            float av[4], wv[4];
            #pragma unroll
            for (int i = 0; i < 4; ++i) av[i] = As[k][(ty << 2) + i];
            #pragma unroll
            for (int i = 0; i < 4; ++i) wv[i] = Ws[k][(tx << 2) + i];
            #pragma unroll
            for (int i = 0; i < 4; ++i)
                #pragma unroll
                for (int j = 0; j < 4; ++j) acc[i][j] = fmaf(av[i], wv[j], acc[i][j]);
        }
        __syncthreads();
    }
    #pragma unroll
    for (int i = 0; i < 4; ++i) {
        int m = bm + (ty << 2) + i;
        #pragma unroll
        for (int j = 0; j < 4; ++j) {
            int n = bn + (tx << 2) + j;
            C[(size_t)m * N + n] = acc[i][j] + bias[n];
        }
    }
}

// ---------- pairwise distance: D2[n,m] = sq[n]+sq[m]-2*H[n]·H[m], one batch ----------
__global__ __launch_bounds__(256) void gemm_d2(
        const float* __restrict__ H, const float* __restrict__ SQ, float* __restrict__ D2)
{
    __shared__ float As[16][65];
    __shared__ float Bs[16][65];
    int tid = threadIdx.x;
    int bm = blockIdx.y * 64, bn = blockIdx.x * 64;
    int tx = tid & 15, ty = tid >> 4;
    int lr = tid >> 2, lk = (tid & 3) << 2;
    float acc[4][4] = {};
    for (int k0 = 0; k0 < 512; k0 += 16) {
        const float* Ap = H + (size_t)(bm + lr) * 512 + (k0 + lk);
        const float* Bp = H + (size_t)(bn + lr) * 512 + (k0 + lk);
        #pragma unroll
        for (int j = 0; j < 4; ++j) As[lk + j][lr] = Ap[j];
        #pragma unroll
        for (int j = 0; j < 4; ++j) Bs[lk + j][lr] = Bp[j];
        __syncthreads();
        #pragma unroll
        for (int k = 0; k < 16; ++k) {
            float av[4], wv[4];
            #pragma unroll
            for (int i = 0; i < 4; ++i) av[i] = As[k][(ty << 2) + i];
            #pragma unroll
            for (int i = 0; i < 4; ++i) wv[i] = Bs[k][(tx << 2) + i];
            #pragma unroll
            for (int i = 0; i < 4; ++i)
                #pragma unroll
                for (int j = 0; j < 4; ++j) acc[i][j] = fmaf(av[i], wv[j], acc[i][j]);
        }
        __syncthreads();
    }
    #pragma unroll
    for (int i = 0; i < 4; ++i) {
        int n = bm + (ty << 2) + i;
        #pragma unroll
        for (int j = 0; j < 4; ++j) {
            int m = bn + (tx << 2) + j;
            D2[(size_t)n * NSEQ + m] = SQ[n] + SQ[m] - 2.f * acc[i][j];
        }
    }
}

// ---------- top-9 smallest (dist, idx) per row ----------
__global__ __launch_bounds__(256) void topk9_k(const float* __restrict__ D2, int* __restrict__ idx)
{
    int n = blockIdx.x, tid = threadIdx.x;
    __shared__ float vals[NSEQ];
    __shared__ float rv[256];
    __shared__ int   ri[256];
    for (int m = tid; m < NSEQ; m += 256)
        vals[m] = fmaxf(D2[(size_t)n * NSEQ + m], 0.f);
    __syncthreads();
    for (int it = 0; it < KNN; ++it) {
        float bv = INFINITY; int bi = 0x7fffffff;
        #pragma unroll
        for (int j = 0; j < 8; ++j) {
            int m = tid + j * 256;
            float v = vals[m];
            if (v < bv) { bv = v; bi = m; }   // j ascending -> keeps smallest m on ties
        }
        rv[tid] = bv; ri[tid] = bi; __syncthreads();
        for (int s = 128; s > 0; s >>= 1) {
            if (tid < s) {
                if (rv[tid + s] < rv[tid] || (rv[tid + s] == rv[tid] && ri[tid + s] < ri[tid])) {
                    rv[tid] = rv[tid + s]; ri[tid] = ri[tid + s];
                }
            }
            __syncthreads();
        }
        int win = ri[0];
        if (tid == 0) { idx[n * KNN + it] = win; vals[win] = INFINITY; }
        __syncthreads();
    }
}

// ---------- GCN aggregate (mean of 9 neighbors) + LN + leaky + residual ----------
__global__ __launch_bounds__(256) void gcn_post(
        const float* __restrict__ s, const int* __restrict__ idx,
        const float* __restrict__ g, const float* __restrict__ be, float* __restrict__ hg)
{
    int row = blockIdx.x, tid = threadIdx.x;
    int bb = row >> 11;
    __shared__ float os[512];
    __shared__ float red[256];
    int id[KNN];
    #pragma unroll
    for (int j = 0; j < KNN; ++j) id[j] = idx[row * KNN + j] + (bb << 11);
    for (int c = tid; c < 512; c += 256) {
        float acc = 0.f;
        #pragma unroll
        for (int j = 0; j < KNN; ++j) acc += s[((size_t)id[j] << 9) + c];
        os[c] = acc * (1.f / 9.f);
    }
    __syncthreads();
    float mean = blockReduceSum(os[tid] + os[tid + 256], red) * (1.f / 512.f);
    float d0 = os[tid] - mean, d1 = os[tid + 256] - mean;
    float var = blockReduceSum(d0 * d0 + d1 * d1, red) * (1.f / 512.f);
    float rs = rsqrtf(var + 1e-5f);
    size_t base = (size_t)row << 9;
    for (int c = tid; c < 512; c += 256) {
        float y = (os[c] - mean) * rs * g[c] + be[c];
        y = y > 0.f ? y : 0.2f * y;
        hg[base + c] = y + hg[base + c];
    }
}

// ---------- y = LN(x + r)*g + b, in place on x ----------
__global__ __launch_bounds__(256) void ln_res(
        float* __restrict__ x, const float* __restrict__ r,
        const float* __restrict__ g, const float* __restrict__ b)
{
    int row = blockIdx.x, tid = threadIdx.x;
    __shared__ float xs[512];
    __shared__ float red[256];
    size_t base = (size_t)row << 9;
    for (int c = tid; c < 512; c += 256) xs[c] = x[base + c] + r[base + c];
    __syncthreads();
    float mean = blockReduceSum(xs[tid] + xs[tid + 256], red) * (1.f / 512.f);
    float d0 = xs[tid] - mean, d1 = xs[tid + 256] - mean;
    float var = blockReduceSum(d0 * d0 + d1 * d1, red) * (1.f / 512.f);
    float rs = rsqrtf(var + 1e-5f);
    for (int c = tid; c < 512; c += 256)
        x[base + c] = (xs[c] - mean) * rs * g[c] + b[c];
}

// ---------- attention: one block per (q, head, batch) ----------
__global__ __launch_bounds__(256) void attn_k(const float* __restrict__ qkv, float* __restrict__ ao)
{
    int q = blockIdx.x, h = blockIdx.y, b = blockIdx.z;
    int tid = threadIdx.x;
    __shared__ float qs[64];
    __shared__ float sc[NSEQ];
    __shared__ float red[256];
    __shared__ float pp[4][64];
    size_t rowbase = ((size_t)(b * NSEQ + q)) * 1536;
    if (tid < 64) qs[tid] = qkv[rowbase + h * 64 + tid];
    __syncthreads();
    for (int m = tid; m < NSEQ; m += 256) {
        const float* kp = qkv + ((size_t)(b * NSEQ + m)) * 1536 + 512 + h * 64;
        float dot = 0.f;
        #pragma unroll
        for (int d = 0; d < 64; ++d) dot = fmaf(qs[d], kp[d], dot);
        sc[m] = dot * 0.125f;
    }
    __syncthreads();
    float mx = -INFINITY;
    for (int m = tid; m < NSEQ; m += 256) mx = fmaxf(mx, sc[m]);
    red[tid] = mx; __syncthreads();
    for (int s = 128; s > 0; s >>= 1) {
        if (tid < s) red[tid] = fmaxf(red[tid], red[tid + s]);
        __syncthreads();
    }
    mx = red[0]; __syncthreads();
    float ssum = 0.f;
    for (int m = tid; m < NSEQ; m += 256) {
        float e = expf(sc[m] - mx);
        sc[m] = e; ssum += e;
    }
    float inv = 1.f / blockReduceSum(ssum, red);
    int g2 = tid >> 6, d = tid & 63;
    float part = 0.f;
    for (int m = g2 * 512; m < g2 * 512 + 512; ++m)
        part = fmaf(sc[m], qkv[((size_t)(b * NSEQ + m)) * 1536 + 1024 + h * 64 + d], part);
    pp[g2][d] = part; __syncthreads();
    if (tid < 64) {
        float r2 = (pp[0][tid] + pp[1][tid] + pp[2][tid] + pp[3][tid]) * inv;
        ao[((size_t)(b * NSEQ + q)) * 512 + h * 64 + tid] = r2;
    }
}

// ---------- elementwise ----------
__global__ void glu_k(const float* __restrict__ vg, float* __restrict__ h) {
    for (int i = blockIdx.x * 256 + threadIdx.x; i < ROWS * 512; i += gridDim.x * 256) {
        int row = i >> 9, c = i & 511;
        float v = vg[((size_t)row << 10) + c];
        float gt = vg[((size_t)row << 10) + 512 + c];
        h[i] = v * (1.f / (1.f + expf(-gt)));
    }
}
__global__ void copy2_k(const float* __restrict__ h, float* __restrict__ hg, float* __restrict__ ht) {
    for (int i = blockIdx.x * 256 + threadIdx.x; i < ROWS * 512; i += gridDim.x * 256) {
        float v = h[i]; hg[i] = v; ht[i] = v;
    }
}
__global__ void gelu_k(float* __restrict__ x, int n) {
    for (int i = blockIdx.x * 256 + threadIdx.x; i < n; i += gridDim.x * 256) {
        float v = x[i];
        x[i] = 0.5f * v * (1.f + erff(v * 0.70710678118654752f));
    }
}
__global__ void tanh_k(float* __restrict__ x, int n) {
    for (int i = blockIdx.x * 256 + threadIdx.x; i < n; i += gridDim.x * 256)
        x[i] = tanhf(x[i]);
}
__global__ void concat_k(const float* __restrict__ hg, const float* __restrict__ ht, float* __restrict__ cat) {
    for (int i = blockIdx.x * 256 + threadIdx.x; i < ROWS * 1024; i += gridDim.x * 256) {
        int row = i >> 10, c = i & 1023;
        cat[i] = (c < 512) ? hg[((size_t)row << 9) + c] : ht[((size_t)row << 9) + c - 512];
    }
}
__global__ __launch_bounds__(256) void rowsq_k(const float* __restrict__ h, float* __restrict__ sq) {
    int row = blockIdx.x, tid = threadIdx.x;
    __shared__ float red[256];
    size_t base = (size_t)row << 9;
    float a = h[base + tid], b2 = h[base + tid + 256];
    float s = blockReduceSum(a * a + b2 * b2, red);
    if (tid == 0) sq[row] = s;
}

// ---------- pooling / classifier ----------
__global__ __launch_bounds__(256) void rowdot_k(const float* __restrict__ t, const float* __restrict__ w2,
                                                const float* __restrict__ b2, float* __restrict__ srow) {
    int row = blockIdx.x, tid = threadIdx.x;
    __shared__ float red[256];
    float s = blockReduceSum(t[(size_t)row * 256 + tid] * w2[tid], red);
    if (tid == 0) srow[row] = s + b2[0];
}
__global__ __launch_bounds__(256) void softmax_n_k(const float* __restrict__ srow, float* __restrict__ a,
                                                   float* __restrict__ out) {
    int b = blockIdx.x, tid = threadIdx.x;
    __shared__ float red[256];
    float mx = -INFINITY;
    for (int n = tid; n < NSEQ; n += 256) mx = fmaxf(mx, srow[b * NSEQ + n]);
    red[tid] = mx; __syncthreads();
    for (int s = 128; s > 0; s >>= 1) {
        if (tid < s) red[tid] = fmaxf(red[tid], red[tid + s]);
        __syncthreads();
    }
    mx = red[0]; __syncthreads();
    float sm = 0.f;
    for (int n = tid; n < NSEQ; n += 256) {
        float e = expf(srow[b * NSEQ + n] - mx);
        a[b * NSEQ + n] = e; sm += e;
    }
    float inv = 1.f / blockReduceSum(sm, red);
    for (int n = tid; n < NSEQ; n += 256) {
        float v = a[b * NSEQ + n] * inv;
        a[b * NSEQ + n] = v;
        out[2 + b * NSEQ + n] = v;
    }
}
__global__ __launch_bounds__(256) void pool_k(const float* __restrict__ hf, const float* __restrict__ a,
                                              float* __restrict__ Mb, float* __restrict__ out) {
    int b = blockIdx.y;
    int c = blockIdx.x * 256 + threadIdx.x;
    const float* ab = a + b * NSEQ;
    const float* hb = hf + (((size_t)b * NSEQ) << 9);
    float acc = 0.f;
    for (int n = 0; n < NSEQ; ++n) acc = fmaf(hb[((size_t)n << 9) + c], ab[n], acc);
    Mb[b * 512 + c] = acc;
    out[2 + ROWS + b * 512 + c] = acc;
}
__global__ __launch_bounds__(256) void classifier_k(const float* __restrict__ Mb,
        const float* __restrict__ w1, const float* __restrict__ b1,
        const float* __restrict__ w2, const float* __restrict__ b2, float* __restrict__ out) {
    int b = blockIdx.x, tid = threadIdx.x;
    __shared__ float Ms[512];
    __shared__ float red[256];
    for (int c = tid; c < 512; c += 256) Ms[c] = Mb[b * 512 + c];
    __syncthreads();
    float acc = 0.f;
    for (int c = 0; c < 512; ++c) acc = fmaf(Ms[c], w1[tid * 512 + c], acc);
    acc += b1[tid];
    float hj = acc > 0.f ? acc : expm1f(acc);   // ELU alpha=1
    float s = blockReduceSum(hj * w2[tid], red);
    if (tid == 0) out[b] = s + b2[0];
}

extern "C" void kernel_launch(void* const* d_in, const int* in_sizes, int n_in,
                              void* d_out, int out_size, void* d_ws, size_t ws_size,
                              hipStream_t stream)
{
    const float* X      = (const float*)d_in[0];
    const float* Wstart = (const float*)d_in[1];
    const float* Bstart = (const float*)d_in[2];
    const float* GluW   = (const float*)d_in[3];
    const float* GluB   = (const float*)d_in[4];
    const float* GcnW   = (const float*)d_in[5];
    const float* GcnB   = (const float*)d_in[6];
    const float* GcnG   = (const float*)d_in[7];
    const float* GcnBe  = (const float*)d_in[8];
    const float* QkvW   = (const float*)d_in[9];
    const float* QkvB   = (const float*)d_in[10];
    const float* OutW   = (const float*)d_in[11];
    const float* OutB   = (const float*)d_in[12];
    const float* Ln1G   = (const float*)d_in[13];
    const float* Ln1B   = (const float*)d_in[14];
    const float* Ffn1W  = (const float*)d_in[15];
    const float* Ffn1B  = (const float*)d_in[16];
    const float* Ffn2W  = (const float*)d_in[17];
    const float* Ffn2B  = (const float*)d_in[18];
    const float* Ln2G   = (const float*)d_in[19];
    const float* Ln2B   = (const float*)d_in[20];
    const float* FusW   = (const float*)d_in[21];
    const float* FusB   = (const float*)d_in[22];
    const float* AW1    = (const float*)d_in[23];
    const float* AB1    = (const float*)d_in[24];
    const float* AW2    = (const float*)d_in[25];
    const float* AB2    = (const float*)d_in[26];
    const float* CW1    = (const float*)d_in[27];
    const float* CB1    = (const float*)d_in[28];
    const float* CW2    = (const float*)d_in[29];
    const float* CB2    = (const float*)d_in[30];
    float* out = (float*)d_out;

    char* w = (char*)d_ws;
    float* h     = (float*)(w);                        // 8MB (also hf later)
    float* hg    = (float*)(w + (8ull  << 20));        // 8MB
    float* ht    = (float*)(w + (16ull << 20));        // 8MB
    float* big   = (float*)(w + (24ull << 20));        // 24MB: vg / d2 / qkv / ff1 / cat
    float* t512a = (float*)(w + (48ull << 20));        // 8MB
    float* t512b = (float*)(w + (56ull << 20));        // 8MB
    float* t256  = (float*)(w + (64ull << 20));        // 4MB
    float* sq    = (float*)(w + (68ull << 20));                 // 16KB
    int*   idx   = (int*)  (w + (68ull << 20) + (1u << 16));    // 144KB
    float* srow  = (float*)(w + (68ull << 20) + (1u << 18));    // 16KB
    float* afb   = (float*)(w + (68ull << 20) + (1u << 18) + (1u << 16));
    float* Mbuf  = (float*)(w + (68ull << 20) + (1u << 18) + (2u << 16));
    float* hf    = h;

    if (ws_size < (70ull << 20)) return;  // insufficient scratch; fail loudly

    dim3 blk(256);

    // fc_start: h_pre = X @ Wstart^T + Bstart
    gemm_bias<<<dim3(8, 64), blk, 0, stream>>>(X, Wstart, Bstart, t512a, ROWS, 512, 1024);
    // GLU
    gemm_bias<<<dim3(16, 64), blk, 0, stream>>>(t512a, GluW, GluB, big, ROWS, 1024, 512);
    glu_k<<<dim3(2048), blk, 0, stream>>>(big, h);
    copy2_k<<<dim3(2048), blk, 0, stream>>>(h, hg, ht);

    // KNN graph
    rowsq_k<<<dim3(ROWS), blk, 0, stream>>>(h, sq);
    for (int b = 0; b < 2; ++b) {
        gemm_d2<<<dim3(32, 32), blk, 0, stream>>>(h + (size_t)b * NSEQ * 512, sq + b * NSEQ, big);
        topk9_k<<<dim3(NSEQ), blk, 0, stream>>>(big, idx + b * NSEQ * KNN);
    }

    // GCN branch
    for (int i = 0; i < 2; ++i) {
        gemm_bias<<<dim3(8, 64), blk, 0, stream>>>(hg, GcnW + (size_t)i * 512 * 512,
                                                   GcnB + i * 512, t512a, ROWS, 512, 512);
        gcn_post<<<dim3(ROWS), blk, 0, stream>>>(t512a, idx, GcnG + i * 512, GcnBe + i * 512, hg);
    }

    // Transformer branch
    for (int i = 0; i < 2; ++i) {
        gemm_bias<<<dim3(24, 64), blk, 0, stream>>>(ht, QkvW + (size_t)i * 1536 * 512,
                                                    QkvB + i * 1536, big, ROWS, 1536, 512);
        attn_k<<<dim3(NSEQ, 8, 2), blk, 0, stream>>>(big, t512a);
        gemm_bias<<<dim3(8, 64), blk, 0, stream>>>(t512a, OutW + (size_t)i * 512 * 512,
                                                   OutB + i * 512, t512b, ROWS, 512, 512);
        ln_res<<<dim3(ROWS), blk, 0, stream>>>(ht, t512b, Ln1G + i * 512, Ln1B + i * 512);
        gemm_bias<<<dim3(16, 64), blk, 0, stream>>>(ht, Ffn1W + (size_t)i * 1024 * 512,
                                                    Ffn1B + i * 1024, big, ROWS, 1024, 512);
        gelu_k<<<dim3(4096), blk, 0, stream>>>(big, ROWS * 1024);
        gemm_bias<<<dim3(8, 64), blk, 0, stream>>>(big, Ffn2W + (size_t)i * 512 * 1024,
                                                   Ffn2B + i * 512, t512a, ROWS, 512, 1024);
        ln_res<<<dim3(ROWS), blk, 0, stream>>>(ht, t512a, Ln2G + i * 512, Ln2B + i * 512);
    }

    // fusion
    concat_k<<<dim3(4096), blk, 0, stream>>>(hg, ht, big);
    gemm_bias<<<dim3(8, 64), blk, 0, stream>>>(big, FusW, FusB, hf, ROWS, 512, 1024);

    // gated attention pooling
    gemm_bias<<<dim3(4, 64), blk, 0, stream>>>(hf, AW1, AB1, t256, ROWS, 256, 512);
    tanh_k<<<dim3(1024), blk, 0, stream>>>(t256, ROWS * 256);
    rowdot_k<<<dim3(ROWS), blk, 0, stream>>>(t256, AW2, AB2, srow);
    softmax_n_k<<<dim3(2), blk, 0, stream>>>(srow, afb, out);
    pool_k<<<dim3(2, 2), blk, 0, stream>>>(hf, afb, Mbuf, out);

    // classifier
    classifier_k<<<dim3(2), blk, 0, stream>>>(Mbuf, CW1, CB1, CW2, CB2, out);
}

// Round 3
// 1796.349 us; speedup vs baseline: 3.8611x; 3.8611x over previous
//
#include <hip/hip_runtime.h>
#include <hip/hip_bf16.h>
#include <math.h>

#define NSEQ 2048
#define ROWS 4096   // B*N
#define KNN 9

typedef short bh8 __attribute__((ext_vector_type(8)));   // 8 bf16 in 4 VGPRs
typedef float f4v __attribute__((ext_vector_type(4)));

__device__ __forceinline__ short f2bf(float f) {
    union { float f; unsigned u; } v; v.f = f;
    unsigned r = (v.u + 0x7fffu + ((v.u >> 16) & 1u)) >> 16;
    return (short)r;
}

// ---------- block reduce helpers (blockDim.x == 256) ----------
__device__ __forceinline__ float blockReduceSum(float v, float* red) {
    int tid = threadIdx.x;
    red[tid] = v; __syncthreads();
    for (int s = 128; s > 0; s >>= 1) {
        if (tid < s) red[tid] += red[tid + s];
        __syncthreads();
    }
    float r = red[0]; __syncthreads();
    return r;
}

// ---------- generic GEMM: C[M,N] = A[M,K] @ W[N,K]^T + bias[N] ----------
__global__ __launch_bounds__(256) void gemm_bias(
        const float* __restrict__ A, const float* __restrict__ W,
        const float* __restrict__ bias, float* __restrict__ C,
        int M, int N, int K)
{
    __shared__ float As[16][65];
    __shared__ float Ws[16][65];
    int tid = threadIdx.x;
    int bm = blockIdx.y * 64, bn = blockIdx.x * 64;
    int tx = tid & 15, ty = tid >> 4;
    int lr = tid >> 2, lk = (tid & 3) << 2;
    float acc[4][4] = {};
    for (int k0 = 0; k0 < K; k0 += 16) {
        const float* Ap = A + (size_t)(bm + lr) * K + (k0 + lk);
        const float* Wp = W + (size_t)(bn + lr) * K + (k0 + lk);
        #pragma unroll
        for (int j = 0; j < 4; ++j) As[lk + j][lr] = Ap[j];
        #pragma unroll
        for (int j = 0; j < 4; ++j) Ws[lk + j][lr] = Wp[j];
        __syncthreads();
        #pragma unroll
        for (int k = 0; k < 16; ++k) {
            float av[4], wv[4];
            #pragma unroll
            for (int i = 0; i < 4; ++i) av[i] = As[k][(ty << 2) + i];
            #pragma unroll
            for (int i = 0; i < 4; ++i) wv[i] = Ws[k][(tx << 2) + i];
            #pragma unroll
            for (int i = 0; i < 4; ++i)
                #pragma unroll
                for (int j = 0; j < 4; ++j) acc[i][j] = fmaf(av[i], wv[j], acc[i][j]);
        }
        __syncthreads();
    }
    #pragma unroll
    for (int i = 0; i < 4; ++i) {
        int m = bm + (ty << 2) + i;
        #pragma unroll
        for (int j = 0; j < 4; ++j) {
            int n = bn + (tx << 2) + j;
            C[(size_t)m * N + n] = acc[i][j] + bias[n];
        }
    }
}

// ---------- pairwise distance ----------
__global__ __launch_bounds__(256) void gemm_d2(
        const float* __restrict__ H, const float* __restrict__ SQ, float* __restrict__ D2)
{
    __shared__ float As[16][65];
    __shared__ float Bs[16][65];
    int tid = threadIdx.x;
    int bm = blockIdx.y * 64, bn = blockIdx.x * 64;
    int tx = tid & 15, ty = tid >> 4;
    int lr = tid >> 2, lk = (tid & 3) << 2;
    float acc[4][4] = {};
    for (int k0 = 0; k0 < 512; k0 += 16) {
        const float* Ap = H + (size_t)(bm + lr) * 512 + (k0 + lk);
        const float* Bp = H + (size_t)(bn + lr) * 512 + (k0 + lk);
        #pragma unroll
        for (int j = 0; j < 4; ++j) As[lk + j][lr] = Ap[j];
        #pragma unroll
        for (int j = 0; j < 4; ++j) Bs[lk + j][lr] = Bp[j];
        __syncthreads();
        #pragma unroll
        for (int k = 0; k < 16; ++k) {
            float av[4], wv[4];
            #pragma unroll
            for (int i = 0; i < 4; ++i) av[i] = As[k][(ty << 2) + i];
            #pragma unroll
            for (int i = 0; i < 4; ++i) wv[i] = Bs[k][(tx << 2) + i];
            #pragma unroll
            for (int i = 0; i < 4; ++i)
                #pragma unroll
                for (int j = 0; j < 4; ++j) acc[i][j] = fmaf(av[i], wv[j], acc[i][j]);
        }
        __syncthreads();
    }
    #pragma unroll
    for (int i = 0; i < 4; ++i) {
        int n = bm + (ty << 2) + i;
        #pragma unroll
        for (int j = 0; j < 4; ++j) {
            int m = bn + (tx << 2) + j;
            D2[(size_t)n * NSEQ + m] = SQ[n] + SQ[m] - 2.f * acc[i][j];
        }
    }
}

// ---------- top-9 smallest per row ----------
__global__ __launch_bounds__(256) void topk9_k(const float* __restrict__ D2, int* __restrict__ idx)
{
    int n = blockIdx.x, tid = threadIdx.x;
    __shared__ float vals[NSEQ];
    __shared__ float rv[256];
    __shared__ int   ri[256];
    for (int m = tid; m < NSEQ; m += 256)
        vals[m] = fmaxf(D2[(size_t)n * NSEQ + m], 0.f);
    __syncthreads();
    for (int it = 0; it < KNN; ++it) {
        float bv = INFINITY; int bi = 0x7fffffff;
        #pragma unroll
        for (int j = 0; j < 8; ++j) {
            int m = tid + j * 256;
            float v = vals[m];
            if (v < bv) { bv = v; bi = m; }
        }
        rv[tid] = bv; ri[tid] = bi; __syncthreads();
        for (int s = 128; s > 0; s >>= 1) {
            if (tid < s) {
                if (rv[tid + s] < rv[tid] || (rv[tid + s] == rv[tid] && ri[tid + s] < ri[tid])) {
                    rv[tid] = rv[tid + s]; ri[tid] = ri[tid + s];
                }
            }
            __syncthreads();
        }
        int win = ri[0];
        if (tid == 0) { idx[n * KNN + it] = win; vals[win] = INFINITY; }
        __syncthreads();
    }
}

// ---------- GCN aggregate + LN + leaky + residual ----------
__global__ __launch_bounds__(256) void gcn_post(
        const float* __restrict__ s, const int* __restrict__ idx,
        const float* __restrict__ g, const float* __restrict__ be, float* __restrict__ hg)
{
    int row = blockIdx.x, tid = threadIdx.x;
    int bb = row >> 11;
    __shared__ float os[512];
    __shared__ float red[256];
    int id[KNN];
    #pragma unroll
    for (int j = 0; j < KNN; ++j) id[j] = idx[row * KNN + j] + (bb << 11);
    for (int c = tid; c < 512; c += 256) {
        float acc = 0.f;
        #pragma unroll
        for (int j = 0; j < KNN; ++j) acc += s[((size_t)id[j] << 9) + c];
        os[c] = acc * (1.f / 9.f);
    }
    __syncthreads();
    float mean = blockReduceSum(os[tid] + os[tid + 256], red) * (1.f / 512.f);
    float d0 = os[tid] - mean, d1 = os[tid + 256] - mean;
    float var = blockReduceSum(d0 * d0 + d1 * d1, red) * (1.f / 512.f);
    float rs = rsqrtf(var + 1e-5f);
    size_t base = (size_t)row << 9;
    for (int c = tid; c < 512; c += 256) {
        float y = (os[c] - mean) * rs * g[c] + be[c];
        y = y > 0.f ? y : 0.2f * y;
        hg[base + c] = y + hg[base + c];
    }
}

// ---------- y = LN(x + r)*g + b ----------
__global__ __launch_bounds__(256) void ln_res(
        float* __restrict__ x, const float* __restrict__ r,
        const float* __restrict__ g, const float* __restrict__ b)
{
    int row = blockIdx.x, tid = threadIdx.x;
    __shared__ float xs[512];
    __shared__ float red[256];
    size_t base = (size_t)row << 9;
    for (int c = tid; c < 512; c += 256) xs[c] = x[base + c] + r[base + c];
    __syncthreads();
    float mean = blockReduceSum(xs[tid] + xs[tid + 256], red) * (1.f / 512.f);
    float d0 = xs[tid] - mean, d1 = xs[tid + 256] - mean;
    float var = blockReduceSum(d0 * d0 + d1 * d1, red) * (1.f / 512.f);
    float rs = rsqrtf(var + 1e-5f);
    for (int c = tid; c < 512; c += 256)
        x[base + c] = (xs[c] - mean) * rs * g[c] + b[c];
}

// ---------- qkv f32 -> Qb (scaled 0.125), Kb bf16, head-major [b,h,n,64] ----------
__global__ __launch_bounds__(256) void qk_convert(const float* __restrict__ qkv,
                                                  short* __restrict__ Qb, short* __restrict__ Kb)
{
    int t = blockIdx.x * 256 + threadIdx.x;     // 524288 threads, 4 elems each
    int o = t * 4;
    int d = o & 63, n = (o >> 6) & 2047, bh = o >> 17;
    int b = bh >> 3, h = bh & 7;
    const float* qp = qkv + ((size_t)(b * NSEQ + n)) * 1536 + h * 64 + d;
    const float4 qv = *(const float4*)qp;
    const float4 kv = *(const float4*)(qp + 512);
    short4 qs, ks;
    qs.x = f2bf(qv.x * 0.125f); qs.y = f2bf(qv.y * 0.125f);
    qs.z = f2bf(qv.z * 0.125f); qs.w = f2bf(qv.w * 0.125f);
    ks.x = f2bf(kv.x); ks.y = f2bf(kv.y); ks.z = f2bf(kv.z); ks.w = f2bf(kv.w);
    *(short4*)(Qb + o) = qs;
    *(short4*)(Kb + o) = ks;
}

// ---------- V -> Vt bf16 transposed [b,h,64(d),2048(n)] ----------
__global__ __launch_bounds__(256) void vt_convert(const float* __restrict__ qkv, short* __restrict__ Vt)
{
    __shared__ float tile[64][65];
    int nt = blockIdx.x, h = blockIdx.y, b = blockIdx.z;
    int t = threadIdx.x;
    #pragma unroll
    for (int it = 0; it < 16; ++it) {
        int i = it * 256 + t; int nl = i >> 6, d = i & 63;
        tile[nl][d] = qkv[((size_t)(b * NSEQ + nt * 64 + nl)) * 1536 + 1024 + h * 64 + d];
    }
    __syncthreads();
    #pragma unroll
    for (int it = 0; it < 16; ++it) {
        int i = it * 256 + t; int d = i >> 6, nl = i & 63;
        Vt[((size_t)((b * 8 + h) * 64 + d)) * NSEQ + nt * 64 + nl] = f2bf(tile[nl][d]);
    }
}

// ---------- flash attention: 4 waves x 16 q-rows, MFMA 16x16x32 bf16 ----------
__global__ __launch_bounds__(256) void flash_attn(
        const short* __restrict__ Qb, const short* __restrict__ Kb,
        const short* __restrict__ Vt, float* __restrict__ ao)
{
    int wid = threadIdx.x >> 6, lane = threadIdx.x & 63;
    int g = lane >> 4, c = lane & 15;
    int h = blockIdx.y, b = blockIdx.z;
    int bh = b * 8 + h;
    int q0 = blockIdx.x * 64 + wid * 16;

    __shared__ char Pl[4][2048];                 // per-wave 16x64 bf16, xor-swizzled
    char* myP = Pl[wid];

    // Q A-fragments: row = c, k(d) = g*8 + j  (two d-halves)
    const short* qbase = Qb + ((size_t)bh * NSEQ + q0 + c) * 64 + g * 8;
    bh8 qa0 = *(const bh8*)(qbase);
    bh8 qa1 = *(const bh8*)(qbase + 32);

    f4v o0 = {0,0,0,0}, o1 = {0,0,0,0}, o2 = {0,0,0,0}, o3 = {0,0,0,0};
    float m[4] = {-INFINITY,-INFINITY,-INFINITY,-INFINITY};
    float l[4] = {0,0,0,0};

    const short* kbb = Kb + (size_t)bh * NSEQ * 64 + g * 8;
    const short* vbb = Vt + (size_t)bh * 64 * NSEQ + g * 8;

    for (int k0 = 0; k0 < NSEQ; k0 += 64) {
        // ---- QK^T: S[16q x 64k] over 4 col-blocks ----
        f4v s[4];
        #pragma unroll
        for (int cb = 0; cb < 4; ++cb) {
            const short* kp = kbb + (size_t)(k0 + cb * 16 + c) * 64;
            bh8 kb0 = *(const bh8*)(kp);
            bh8 kb1 = *(const bh8*)(kp + 32);
            f4v acc = {0,0,0,0};
            acc = __builtin_amdgcn_mfma_f32_16x16x32_bf16(qa0, kb0, acc, 0, 0, 0);
            acc = __builtin_amdgcn_mfma_f32_16x16x32_bf16(qa1, kb1, acc, 0, 0, 0);
            s[cb] = acc;
        }
        // ---- online softmax stats (rows g*4+r live in 16 lanes of this group) ----
        float mt[4], rs[4], al[4];
        #pragma unroll
        for (int r = 0; r < 4; ++r) {
            float v = fmaxf(fmaxf(s[0][r], s[1][r]), fmaxf(s[2][r], s[3][r]));
            v = fmaxf(v, __shfl_xor(v, 1));
            v = fmaxf(v, __shfl_xor(v, 2));
            v = fmaxf(v, __shfl_xor(v, 4));
            v = fmaxf(v, __shfl_xor(v, 8));
            mt[r] = v;
        }
        #pragma unroll
        for (int r = 0; r < 4; ++r) {
            float mn = fmaxf(m[r], mt[r]);
            al[r] = __expf(m[r] - mn);
            m[r] = mn;
            rs[r] = 0.f;
        }
        // P = exp(S - m), write bf16 to swizzled LDS
        #pragma unroll
        for (int cb = 0; cb < 4; ++cb) {
            #pragma unroll
            for (int r = 0; r < 4; ++r) {
                float p = __expf(s[cb][r] - m[r]);
                rs[r] += p;
                int row = g * 4 + r;
                int byte = row * 128 + (((cb * 16 + c) * 2) ^ ((row & 7) << 4));
                *(short*)(myP + byte) = f2bf(p);
            }
        }
        #pragma unroll
        for (int r = 0; r < 4; ++r) {
            float v = rs[r];
            v += __shfl_xor(v, 1);
            v += __shfl_xor(v, 2);
            v += __shfl_xor(v, 4);
            v += __shfl_xor(v, 8);
            l[r] = al[r] * l[r] + v;
        }
        f4v alv; alv[0] = al[0]; alv[1] = al[1]; alv[2] = al[2]; alv[3] = al[3];
        o0 *= alv; o1 *= alv; o2 *= alv; o3 *= alv;
        // ---- PV: A = P (row=c, k=g*8+j via swizzled LDS), B = Vt fragments ----
        bh8 pa0 = *(const bh8*)(myP + c * 128 + (( 0 + g * 16) ^ ((c & 7) << 4)));
        bh8 pa1 = *(const bh8*)(myP + c * 128 + ((64 + g * 16) ^ ((c & 7) << 4)));
        #pragma unroll
        for (int db = 0; db < 4; ++db) {
            const short* vp = vbb + (size_t)(db * 16 + c) * NSEQ + k0;
            bh8 vb0 = *(const bh8*)(vp);
            bh8 vb1 = *(const bh8*)(vp + 32);
            f4v* op = (db == 0) ? &o0 : (db == 1) ? &o1 : (db == 2) ? &o2 : &o3;
            *op = __builtin_amdgcn_mfma_f32_16x16x32_bf16(pa0, vb0, *op, 0, 0, 0);
            *op = __builtin_amdgcn_mfma_f32_16x16x32_bf16(pa1, vb1, *op, 0, 0, 0);
        }
    }
    float linv[4];
    #pragma unroll
    for (int r = 0; r < 4; ++r) linv[r] = 1.f / l[r];
    #pragma unroll
    for (int r = 0; r < 4; ++r) {
        size_t rb = ((size_t)(b * NSEQ + q0 + g * 4 + r)) * 512 + h * 64 + c;
        ao[rb]      = o0[r] * linv[r];
        ao[rb + 16] = o1[r] * linv[r];
        ao[rb + 32] = o2[r] * linv[r];
        ao[rb + 48] = o3[r] * linv[r];
    }
}

// ---------- elementwise ----------
__global__ void glu_k(const float* __restrict__ vg, float* __restrict__ h) {
    for (int i = blockIdx.x * 256 + threadIdx.x; i < ROWS * 512; i += gridDim.x * 256) {
        int row = i >> 9, c = i & 511;
        float v = vg[((size_t)row << 10) + c];
        float gt = vg[((size_t)row << 10) + 512 + c];
        h[i] = v * (1.f / (1.f + expf(-gt)));
    }
}
__global__ void copy2_k(const float* __restrict__ h, float* __restrict__ hg, float* __restrict__ ht) {
    for (int i = blockIdx.x * 256 + threadIdx.x; i < ROWS * 512; i += gridDim.x * 256) {
        float v = h[i]; hg[i] = v; ht[i] = v;
    }
}
__global__ void gelu_k(float* __restrict__ x, int n) {
    for (int i = blockIdx.x * 256 + threadIdx.x; i < n; i += gridDim.x * 256) {
        float v = x[i];
        x[i] = 0.5f * v * (1.f + erff(v * 0.70710678118654752f));
    }
}
__global__ void tanh_k(float* __restrict__ x, int n) {
    for (int i = blockIdx.x * 256 + threadIdx.x; i < n; i += gridDim.x * 256)
        x[i] = tanhf(x[i]);
}
__global__ void concat_k(const float* __restrict__ hg, const float* __restrict__ ht, float* __restrict__ cat) {
    for (int i = blockIdx.x * 256 + threadIdx.x; i < ROWS * 1024; i += gridDim.x * 256) {
        int row = i >> 10, c = i & 1023;
        cat[i] = (c < 512) ? hg[((size_t)row << 9) + c] : ht[((size_t)row << 9) + c - 512];
    }
}
__global__ __launch_bounds__(256) void rowsq_k(const float* __restrict__ h, float* __restrict__ sq) {
    int row = blockIdx.x, tid = threadIdx.x;
    __shared__ float red[256];
    size_t base = (size_t)row << 9;
    float a = h[base + tid], b2 = h[base + tid + 256];
    float s = blockReduceSum(a * a + b2 * b2, red);
    if (tid == 0) sq[row] = s;
}

// ---------- pooling / classifier ----------
__global__ __launch_bounds__(256) void rowdot_k(const float* __restrict__ t, const float* __restrict__ w2,
                                                const float* __restrict__ b2, float* __restrict__ srow) {
    int row = blockIdx.x, tid = threadIdx.x;
    __shared__ float red[256];
    float s = blockReduceSum(t[(size_t)row * 256 + tid] * w2[tid], red);
    if (tid == 0) srow[row] = s + b2[0];
}
__global__ __launch_bounds__(256) void softmax_n_k(const float* __restrict__ srow, float* __restrict__ a,
                                                   float* __restrict__ out) {
    int b = blockIdx.x, tid = threadIdx.x;
    __shared__ float red[256];
    float mx = -INFINITY;
    for (int n = tid; n < NSEQ; n += 256) mx = fmaxf(mx, srow[b * NSEQ + n]);
    red[tid] = mx; __syncthreads();
    for (int s = 128; s > 0; s >>= 1) {
        if (tid < s) red[tid] = fmaxf(red[tid], red[tid + s]);
        __syncthreads();
    }
    mx = red[0]; __syncthreads();
    float sm = 0.f;
    for (int n = tid; n < NSEQ; n += 256) {
        float e = expf(srow[b * NSEQ + n] - mx);
        a[b * NSEQ + n] = e; sm += e;
    }
    float inv = 1.f / blockReduceSum(sm, red);
    for (int n = tid; n < NSEQ; n += 256) {
        float v = a[b * NSEQ + n] * inv;
        a[b * NSEQ + n] = v;
        out[2 + b * NSEQ + n] = v;
    }
}
__global__ __launch_bounds__(256) void pool_k(const float* __restrict__ hf, const float* __restrict__ a,
                                              float* __restrict__ Mb, float* __restrict__ out) {
    int b = blockIdx.y;
    int c = blockIdx.x * 256 + threadIdx.x;
    const float* ab = a + b * NSEQ;
    const float* hb = hf + (((size_t)b * NSEQ) << 9);
    float acc = 0.f;
    for (int n = 0; n < NSEQ; ++n) acc = fmaf(hb[((size_t)n << 9) + c], ab[n], acc);
    Mb[b * 512 + c] = acc;
    out[2 + ROWS + b * 512 + c] = acc;
}
__global__ __launch_bounds__(256) void classifier_k(const float* __restrict__ Mb,
        const float* __restrict__ w1, const float* __restrict__ b1,
        const float* __restrict__ w2, const float* __restrict__ b2, float* __restrict__ out) {
    int b = blockIdx.x, tid = threadIdx.x;
    __shared__ float Ms[512];
    __shared__ float red[256];
    for (int c = tid; c < 512; c += 256) Ms[c] = Mb[b * 512 + c];
    __syncthreads();
    float acc = 0.f;
    for (int c = 0; c < 512; ++c) acc = fmaf(Ms[c], w1[tid * 512 + c], acc);
    acc += b1[tid];
    float hj = acc > 0.f ? acc : expm1f(acc);   // ELU alpha=1
    float s = blockReduceSum(hj * w2[tid], red);
    if (tid == 0) out[b] = s + b2[0];
}

extern "C" void kernel_launch(void* const* d_in, const int* in_sizes, int n_in,
                              void* d_out, int out_size, void* d_ws, size_t ws_size,
                              hipStream_t stream)
{
    const float* X      = (const float*)d_in[0];
    const float* Wstart = (const float*)d_in[1];
    const float* Bstart = (const float*)d_in[2];
    const float* GluW   = (const float*)d_in[3];
    const float* GluB   = (const float*)d_in[4];
    const float* GcnW   = (const float*)d_in[5];
    const float* GcnB   = (const float*)d_in[6];
    const float* GcnG   = (const float*)d_in[7];
    const float* GcnBe  = (const float*)d_in[8];
    const float* QkvW   = (const float*)d_in[9];
    const float* QkvB   = (const float*)d_in[10];
    const float* OutW   = (const float*)d_in[11];
    const float* OutB   = (const float*)d_in[12];
    const float* Ln1G   = (const float*)d_in[13];
    const float* Ln1B   = (const float*)d_in[14];
    const float* Ffn1W  = (const float*)d_in[15];
    const float* Ffn1B  = (const float*)d_in[16];
    const float* Ffn2W  = (const float*)d_in[17];
    const float* Ffn2B  = (const float*)d_in[18];
    const float* Ln2G   = (const float*)d_in[19];
    const float* Ln2B   = (const float*)d_in[20];
    const float* FusW   = (const float*)d_in[21];
    const float* FusB   = (const float*)d_in[22];
    const float* AW1    = (const float*)d_in[23];
    const float* AB1    = (const float*)d_in[24];
    const float* AW2    = (const float*)d_in[25];
    const float* AB2    = (const float*)d_in[26];
    const float* CW1    = (const float*)d_in[27];
    const float* CB1    = (const float*)d_in[28];
    const float* CW2    = (const float*)d_in[29];
    const float* CB2    = (const float*)d_in[30];
    float* out = (float*)d_out;

    char* w = (char*)d_ws;
    float* h     = (float*)(w);                        // 8MB (also hf later)
    float* hg    = (float*)(w + (8ull  << 20));        // 8MB
    float* ht    = (float*)(w + (16ull << 20));        // 8MB
    float* big   = (float*)(w + (24ull << 20));        // 24MB: vg / d2 / qkv / ff1 / cat
    float* t512a = (float*)(w + (48ull << 20));        // 8MB
    float* t512b = (float*)(w + (56ull << 20));        // 8MB (Qb/Kb during attention)
    float* t256  = (float*)(w + (64ull << 20));        // 4MB (Vt during attention)
    float* sq    = (float*)(w + (68ull << 20));
    int*   idx   = (int*)  (w + (68ull << 20) + (1u << 16));
    float* srow  = (float*)(w + (68ull << 20) + (1u << 18));
    float* afb   = (float*)(w + (68ull << 20) + (1u << 18) + (1u << 16));
    float* Mbuf  = (float*)(w + (68ull << 20) + (1u << 18) + (2u << 16));
    float* hf    = h;
    short* Qb    = (short*)t512b;            // 4MB
    short* Kb    = Qb + (size_t)2 * 8 * NSEQ * 64;   // 4MB
    short* Vt    = (short*)t256;             // 4MB

    if (ws_size < (70ull << 20)) return;

    dim3 blk(256);

    gemm_bias<<<dim3(8, 64), blk, 0, stream>>>(X, Wstart, Bstart, t512a, ROWS, 512, 1024);
    gemm_bias<<<dim3(16, 64), blk, 0, stream>>>(t512a, GluW, GluB, big, ROWS, 1024, 512);
    glu_k<<<dim3(2048), blk, 0, stream>>>(big, h);
    copy2_k<<<dim3(2048), blk, 0, stream>>>(h, hg, ht);

    rowsq_k<<<dim3(ROWS), blk, 0, stream>>>(h, sq);
    for (int b = 0; b < 2; ++b) {
        gemm_d2<<<dim3(32, 32), blk, 0, stream>>>(h + (size_t)b * NSEQ * 512, sq + b * NSEQ, big);
        topk9_k<<<dim3(NSEQ), blk, 0, stream>>>(big, idx + b * NSEQ * KNN);
    }

    for (int i = 0; i < 2; ++i) {
        gemm_bias<<<dim3(8, 64), blk, 0, stream>>>(hg, GcnW + (size_t)i * 512 * 512,
                                                   GcnB + i * 512, t512a, ROWS, 512, 512);
        gcn_post<<<dim3(ROWS), blk, 0, stream>>>(t512a, idx, GcnG + i * 512, GcnBe + i * 512, hg);
    }

    for (int i = 0; i < 2; ++i) {
        gemm_bias<<<dim3(24, 64), blk, 0, stream>>>(ht, QkvW + (size_t)i * 1536 * 512,
                                                    QkvB + i * 1536, big, ROWS, 1536, 512);
        qk_convert<<<dim3(2048), blk, 0, stream>>>(big, Qb, Kb);
        vt_convert<<<dim3(32, 8, 2), blk, 0, stream>>>(big, Vt);
        flash_attn<<<dim3(32, 8, 2), blk, 0, stream>>>(Qb, Kb, Vt, t512a);
        gemm_bias<<<dim3(8, 64), blk, 0, stream>>>(t512a, OutW + (size_t)i * 512 * 512,
                                                   OutB + i * 512, t512b ? (float*)((char*)d_ws + (40ull << 20)) : nullptr, ROWS, 512, 512);
        // NOTE: out-proj result goes to 40MB..48MB region (big is free after converts)
        ln_res<<<dim3(ROWS), blk, 0, stream>>>(ht, (float*)((char*)d_ws + (40ull << 20)), Ln1G + i * 512, Ln1B + i * 512);
        gemm_bias<<<dim3(16, 64), blk, 0, stream>>>(ht, Ffn1W + (size_t)i * 1024 * 512,
                                                    Ffn1B + i * 1024, big, ROWS, 1024, 512);
        gelu_k<<<dim3(4096), blk, 0, stream>>>(big, ROWS * 1024);
        gemm_bias<<<dim3(8, 64), blk, 0, stream>>>(big, Ffn2W + (size_t)i * 512 * 1024,
                                                   Ffn2B + i * 512, t512a, ROWS, 512, 1024);
        ln_res<<<dim3(ROWS), blk, 0, stream>>>(ht, t512a, Ln2G + i * 512, Ln2B + i * 512);
    }

    concat_k<<<dim3(4096), blk, 0, stream>>>(hg, ht, big);
    gemm_bias<<<dim3(8, 64), blk, 0, stream>>>(big, FusW, FusB, hf, ROWS, 512, 1024);

    gemm_bias<<<dim3(4, 64), blk, 0, stream>>>(hf, AW1, AB1, t256, ROWS, 256, 512);
    tanh_k<<<dim3(1024), blk, 0, stream>>>(t256, ROWS * 256);
    rowdot_k<<<dim3(ROWS), blk, 0, stream>>>(t256, AW2, AB2, srow);
    softmax_n_k<<<dim3(2), blk, 0, stream>>>(srow, afb, out);
    pool_k<<<dim3(2, 2), blk, 0, stream>>>(hf, afb, Mbuf, out);

    classifier_k<<<dim3(2), blk, 0, stream>>>(Mbuf, CW1, CB1, CW2, CB2, out);
}

// Round 4
// 744.869 us; speedup vs baseline: 9.3116x; 2.4116x over previous
//
#include <hip/hip_runtime.h>
#include <hip/hip_bf16.h>
#include <math.h>

#define NSEQ 2048
#define ROWS 4096   // B*N
#define KNN 9
#define MB (1ull << 20)

typedef short bh8 __attribute__((ext_vector_type(8)));   // 8 bf16 in 4 VGPRs
typedef float f4v __attribute__((ext_vector_type(4)));

__device__ __forceinline__ short f2bf(float f) {
    union { float f; unsigned u; } v; v.f = f;
    unsigned r = (v.u + 0x7fffu + ((v.u >> 16) & 1u)) >> 16;
    return (short)r;
}
__device__ __forceinline__ float b2f(short s) {
    union { unsigned u; float f; } v; v.u = ((unsigned)(unsigned short)s) << 16; return v.f;
}

// async global->LDS, 16B per lane; LDS dest is wave-uniform base + lane*16
__device__ __forceinline__ void gload16(const void* g, void* l) {
    __builtin_amdgcn_global_load_lds(
        (const __attribute__((address_space(1))) void*)g,
        (__attribute__((address_space(3))) void*)l, 16, 0, 0);
}

// ---------- block reduce (blockDim.x == 256) ----------
__device__ __forceinline__ float blockReduceSum(float v, float* red) {
    int tid = threadIdx.x;
    red[tid] = v; __syncthreads();
    for (int s = 128; s > 0; s >>= 1) {
        if (tid < s) red[tid] += red[tid + s];
        __syncthreads();
    }
    float r = red[0]; __syncthreads();
    return r;
}

// ---------- f32 -> bf16 conversion (weights + X), 10 segments ----------
struct CvtArgs { const float* src[10]; short* dst[10]; int n4[10]; };
__global__ __launch_bounds__(256) void cvt_k(CvtArgs a) {
    int s = blockIdx.y;
    const float* sp = a.src[s]; short* dp = a.dst[s]; int n = a.n4[s];
    for (int i = blockIdx.x * 256 + threadIdx.x; i < n; i += gridDim.x * 256) {
        float4 v = ((const float4*)sp)[i];
        short4 o; o.x = f2bf(v.x); o.y = f2bf(v.y); o.z = f2bf(v.z); o.w = f2bf(v.w);
        ((short4*)dp)[i] = o;
    }
}

// ---------- MFMA GEMM: C[M,N] = A[M,K](bf16) @ W[N,K](bf16)^T + bias ----------
// 128x128 tile, BK=64, 4 waves (2x2), each wave 4x4 frags of 16x16.
// OUTMODE: 0 = f32, 1 = bf16, 2 = both
template <int OUTMODE>
__global__ __launch_bounds__(256) void mfma_gemm(
        const short* __restrict__ A, const short* __restrict__ W,
        const float* __restrict__ bias, float* __restrict__ Cf, short* __restrict__ Cb,
        int M, int N, int K)
{
    __shared__ short As[128 * 64];
    __shared__ short Bs[128 * 64];
    int tid = threadIdx.x;
    int wv = tid >> 6, l = tid & 63;
    int g = l >> 4, c = l & 15;
    int wr = wv >> 1, wc = wv & 1;
    int bm = blockIdx.y * 128, bn = blockIdx.x * 128;
    int srowo = wv * 32 + (l >> 3);
    int scol = (l & 7) * 8;
    const short* Ap = A + (size_t)(bm + srowo) * K + scol;
    const short* Wp = W + (size_t)(bn + srowo) * K + scol;
    short* AsB = As + (wv * 32) * 64;
    short* BsB = Bs + (wv * 32) * 64;
    f4v acc[4][4] = {};
    for (int k0 = 0; k0 < K; k0 += 64) {
        __syncthreads();
        #pragma unroll
        for (int j = 0; j < 4; ++j) {
            gload16(Ap + (size_t)(j * 8) * K + k0, AsB + j * 8 * 64);
            gload16(Wp + (size_t)(j * 8) * K + k0, BsB + j * 8 * 64);
        }
        __syncthreads();
        #pragma unroll
        for (int ks = 0; ks < 2; ++ks) {
            bh8 af[4], bf_[4];
            #pragma unroll
            for (int mi = 0; mi < 4; ++mi)
                af[mi] = *(const bh8*)(As + (wr * 64 + mi * 16 + c) * 64 + ks * 32 + g * 8);
            #pragma unroll
            for (int ni = 0; ni < 4; ++ni)
                bf_[ni] = *(const bh8*)(Bs + (wc * 64 + ni * 16 + c) * 64 + ks * 32 + g * 8);
            #pragma unroll
            for (int mi = 0; mi < 4; ++mi)
                #pragma unroll
                for (int ni = 0; ni < 4; ++ni)
                    acc[mi][ni] = __builtin_amdgcn_mfma_f32_16x16x32_bf16(af[mi], bf_[ni], acc[mi][ni], 0, 0, 0);
        }
    }
    #pragma unroll
    for (int mi = 0; mi < 4; ++mi) {
        int row = bm + wr * 64 + mi * 16 + g * 4;
        #pragma unroll
        for (int ni = 0; ni < 4; ++ni) {
            int col = bn + wc * 64 + ni * 16 + c;
            float bv = bias[col];
            #pragma unroll
            for (int rr = 0; rr < 4; ++rr) {
                float v = acc[mi][ni][rr] + bv;
                if (OUTMODE != 1) Cf[(size_t)(row + rr) * N + col] = v;
                if (OUTMODE != 0) Cb[(size_t)(row + rr) * N + col] = f2bf(v);
            }
        }
    }
}

// ---------- gram for KNN distances, hi/lo split (f32-equivalent precision) ----------
// D2[n,m] = SQ[n]+SQ[m] - 2*(hi.hi + hi.lo + lo.hi)   [2048x2048, K=512]
__global__ __launch_bounds__(256) void mfma_gram(
        const short* __restrict__ Hi, const short* __restrict__ Lo,
        const float* __restrict__ SQ, float* __restrict__ D2)
{
    __shared__ short HiR[128 * 64], LoR[128 * 64], HiC[128 * 64], LoC[128 * 64];
    int tid = threadIdx.x;
    int wv = tid >> 6, l = tid & 63;
    int g = l >> 4, c = l & 15;
    int wr = wv >> 1, wc = wv & 1;
    int bm = blockIdx.y * 128, bn = blockIdx.x * 128;
    int srowo = wv * 32 + (l >> 3);
    int scol = (l & 7) * 8;
    const short* hiR = Hi + (size_t)(bm + srowo) * 512 + scol;
    const short* loR = Lo + (size_t)(bm + srowo) * 512 + scol;
    const short* hiC = Hi + (size_t)(bn + srowo) * 512 + scol;
    const short* loC = Lo + (size_t)(bn + srowo) * 512 + scol;
    int ldsOff = (wv * 32) * 64;
    f4v acc[4][4] = {};
    for (int k0 = 0; k0 < 512; k0 += 64) {
        __syncthreads();
        #pragma unroll
        for (int j = 0; j < 4; ++j) {
            gload16(hiR + (size_t)(j * 8) * 512 + k0, HiR + ldsOff + j * 8 * 64);
            gload16(loR + (size_t)(j * 8) * 512 + k0, LoR + ldsOff + j * 8 * 64);
            gload16(hiC + (size_t)(j * 8) * 512 + k0, HiC + ldsOff + j * 8 * 64);
            gload16(loC + (size_t)(j * 8) * 512 + k0, LoC + ldsOff + j * 8 * 64);
        }
        __syncthreads();
        #pragma unroll
        for (int ks = 0; ks < 2; ++ks) {
            bh8 hr[4], lr_[4], hc[4], lc[4];
            #pragma unroll
            for (int mi = 0; mi < 4; ++mi) {
                int o = (wr * 64 + mi * 16 + c) * 64 + ks * 32 + g * 8;
                hr[mi] = *(const bh8*)(HiR + o);
                lr_[mi] = *(const bh8*)(LoR + o);
            }
            #pragma unroll
            for (int ni = 0; ni < 4; ++ni) {
                int o = (wc * 64 + ni * 16 + c) * 64 + ks * 32 + g * 8;
                hc[ni] = *(const bh8*)(HiC + o);
                lc[ni] = *(const bh8*)(LoC + o);
            }
            #pragma unroll
            for (int mi = 0; mi < 4; ++mi)
                #pragma unroll
                for (int ni = 0; ni < 4; ++ni) {
                    acc[mi][ni] = __builtin_amdgcn_mfma_f32_16x16x32_bf16(hr[mi], hc[ni], acc[mi][ni], 0, 0, 0);
                    acc[mi][ni] = __builtin_amdgcn_mfma_f32_16x16x32_bf16(hr[mi], lc[ni], acc[mi][ni], 0, 0, 0);
                    acc[mi][ni] = __builtin_amdgcn_mfma_f32_16x16x32_bf16(lr_[mi], hc[ni], acc[mi][ni], 0, 0, 0);
                }
        }
    }
    #pragma unroll
    for (int mi = 0; mi < 4; ++mi) {
        int row = bm + wr * 64 + mi * 16 + g * 4;
        #pragma unroll
        for (int ni = 0; ni < 4; ++ni) {
            int col = bn + wc * 64 + ni * 16 + c;
            float sqc = SQ[col];
            #pragma unroll
            for (int rr = 0; rr < 4; ++rr)
                D2[(size_t)(row + rr) * NSEQ + col] = SQ[row + rr] + sqc - 2.f * acc[mi][ni][rr];
        }
    }
}

// ---------- top-9 smallest per row ----------
__global__ __launch_bounds__(256) void topk9_k(const float* __restrict__ D2, int* __restrict__ idx)
{
    int n = blockIdx.x, tid = threadIdx.x;
    __shared__ float vals[NSEQ];
    __shared__ float rv[256];
    __shared__ int   ri[256];
    for (int m = tid; m < NSEQ; m += 256)
        vals[m] = fmaxf(D2[(size_t)n * NSEQ + m], 0.f);
    __syncthreads();
    for (int it = 0; it < KNN; ++it) {
        float bv = INFINITY; int bi = 0x7fffffff;
        #pragma unroll
        for (int j = 0; j < 8; ++j) {
            int m = tid + j * 256;
            float v = vals[m];
            if (v < bv) { bv = v; bi = m; }
        }
        rv[tid] = bv; ri[tid] = bi; __syncthreads();
        for (int s = 128; s > 0; s >>= 1) {
            if (tid < s) {
                if (rv[tid + s] < rv[tid] || (rv[tid + s] == rv[tid] && ri[tid + s] < ri[tid])) {
                    rv[tid] = rv[tid + s]; ri[tid] = ri[tid + s];
                }
            }
            __syncthreads();
        }
        int win = ri[0];
        if (tid == 0) { idx[n * KNN + it] = win; vals[win] = INFINITY; }
        __syncthreads();
    }
}

// ---------- GCN aggregate + LN + leaky + residual (writes f32 + bf16) ----------
__global__ __launch_bounds__(256) void gcn_post(
        const float* __restrict__ s, const int* __restrict__ idx,
        const float* __restrict__ g, const float* __restrict__ be,
        float* __restrict__ hg, short* __restrict__ hgb)
{
    int row = blockIdx.x, tid = threadIdx.x;
    int bb = row >> 11;
    __shared__ float os[512];
    __shared__ float red[256];
    int id[KNN];
    #pragma unroll
    for (int j = 0; j < KNN; ++j) id[j] = idx[row * KNN + j] + (bb << 11);
    for (int c = tid; c < 512; c += 256) {
        float acc = 0.f;
        #pragma unroll
        for (int j = 0; j < KNN; ++j) acc += s[((size_t)id[j] << 9) + c];
        os[c] = acc * (1.f / 9.f);
    }
    __syncthreads();
    float mean = blockReduceSum(os[tid] + os[tid + 256], red) * (1.f / 512.f);
    float d0 = os[tid] - mean, d1 = os[tid + 256] - mean;
    float var = blockReduceSum(d0 * d0 + d1 * d1, red) * (1.f / 512.f);
    float rs = rsqrtf(var + 1e-5f);
    size_t base = (size_t)row << 9;
    for (int c = tid; c < 512; c += 256) {
        float y = (os[c] - mean) * rs * g[c] + be[c];
        y = y > 0.f ? y : 0.2f * y;
        float nv = y + hg[base + c];
        hg[base + c] = nv;
        hgb[base + c] = f2bf(nv);
    }
}

// ---------- x = LN(x + r)*g + b (writes f32 + bf16) ----------
__global__ __launch_bounds__(256) void ln_res(
        float* __restrict__ x, const float* __restrict__ r,
        const float* __restrict__ g, const float* __restrict__ b, short* __restrict__ xb)
{
    int row = blockIdx.x, tid = threadIdx.x;
    __shared__ float xs[512];
    __shared__ float red[256];
    size_t base = (size_t)row << 9;
    for (int c = tid; c < 512; c += 256) xs[c] = x[base + c] + r[base + c];
    __syncthreads();
    float mean = blockReduceSum(xs[tid] + xs[tid + 256], red) * (1.f / 512.f);
    float d0 = xs[tid] - mean, d1 = xs[tid + 256] - mean;
    float var = blockReduceSum(d0 * d0 + d1 * d1, red) * (1.f / 512.f);
    float rs = rsqrtf(var + 1e-5f);
    for (int c = tid; c < 512; c += 256) {
        float y = (xs[c] - mean) * rs * g[c] + b[c];
        x[base + c] = y;
        xb[base + c] = f2bf(y);
    }
}

// ---------- qkv f32 -> Qb (scaled 0.125), Kb bf16, head-major [b,h,n,64] ----------
__global__ __launch_bounds__(256) void qk_convert(const float* __restrict__ qkv,
                                                  short* __restrict__ Qb, short* __restrict__ Kb)
{
    int t = blockIdx.x * 256 + threadIdx.x;
    int o = t * 4;
    int d = o & 63, n = (o >> 6) & 2047, bh = o >> 17;
    int b = bh >> 3, h = bh & 7;
    const float* qp = qkv + ((size_t)(b * NSEQ + n)) * 1536 + h * 64 + d;
    const float4 qv = *(const float4*)qp;
    const float4 kv = *(const float4*)(qp + 512);
    short4 qs, ks;
    qs.x = f2bf(qv.x * 0.125f); qs.y = f2bf(qv.y * 0.125f);
    qs.z = f2bf(qv.z * 0.125f); qs.w = f2bf(qv.w * 0.125f);
    ks.x = f2bf(kv.x); ks.y = f2bf(kv.y); ks.z = f2bf(kv.z); ks.w = f2bf(kv.w);
    *(short4*)(Qb + o) = qs;
    *(short4*)(Kb + o) = ks;
}

// ---------- V -> Vt bf16 transposed [b,h,64(d),2048(n)] ----------
__global__ __launch_bounds__(256) void vt_convert(const float* __restrict__ qkv, short* __restrict__ Vt)
{
    __shared__ float tile[64][65];
    int nt = blockIdx.x, h = blockIdx.y, b = blockIdx.z;
    int t = threadIdx.x;
    #pragma unroll
    for (int it = 0; it < 16; ++it) {
        int i = it * 256 + t; int nl = i >> 6, d = i & 63;
        tile[nl][d] = qkv[((size_t)(b * NSEQ + nt * 64 + nl)) * 1536 + 1024 + h * 64 + d];
    }
    __syncthreads();
    #pragma unroll
    for (int it = 0; it < 16; ++it) {
        int i = it * 256 + t; int d = i >> 6, nl = i & 63;
        Vt[((size_t)((b * 8 + h) * 64 + d)) * NSEQ + nt * 64 + nl] = f2bf(tile[nl][d]);
    }
}

// ---------- flash attention (bf16 output) ----------
__global__ __launch_bounds__(256) void flash_attn(
        const short* __restrict__ Qb, const short* __restrict__ Kb,
        const short* __restrict__ Vt, short* __restrict__ ao)
{
    int wid = threadIdx.x >> 6, lane = threadIdx.x & 63;
    int g = lane >> 4, c = lane & 15;
    int h = blockIdx.y, b = blockIdx.z;
    int bh = b * 8 + h;
    int q0 = blockIdx.x * 64 + wid * 16;

    __shared__ char Pl[4][2048];
    char* myP = Pl[wid];

    const short* qbase = Qb + ((size_t)bh * NSEQ + q0 + c) * 64 + g * 8;
    bh8 qa0 = *(const bh8*)(qbase);
    bh8 qa1 = *(const bh8*)(qbase + 32);

    f4v o0 = {0,0,0,0}, o1 = {0,0,0,0}, o2 = {0,0,0,0}, o3 = {0,0,0,0};
    float m[4] = {-INFINITY,-INFINITY,-INFINITY,-INFINITY};
    float l[4] = {0,0,0,0};

    const short* kbb = Kb + (size_t)bh * NSEQ * 64 + g * 8;
    const short* vbb = Vt + (size_t)bh * 64 * NSEQ + g * 8;

    for (int k0 = 0; k0 < NSEQ; k0 += 64) {
        f4v s[4];
        #pragma unroll
        for (int cb = 0; cb < 4; ++cb) {
            const short* kp = kbb + (size_t)(k0 + cb * 16 + c) * 64;
            bh8 kb0 = *(const bh8*)(kp);
            bh8 kb1 = *(const bh8*)(kp + 32);
            f4v acc = {0,0,0,0};
            acc = __builtin_amdgcn_mfma_f32_16x16x32_bf16(qa0, kb0, acc, 0, 0, 0);
            acc = __builtin_amdgcn_mfma_f32_16x16x32_bf16(qa1, kb1, acc, 0, 0, 0);
            s[cb] = acc;
        }
        float mt[4], rs[4], al[4];
        #pragma unroll
        for (int r = 0; r < 4; ++r) {
            float v = fmaxf(fmaxf(s[0][r], s[1][r]), fmaxf(s[2][r], s[3][r]));
            v = fmaxf(v, __shfl_xor(v, 1));
            v = fmaxf(v, __shfl_xor(v, 2));
            v = fmaxf(v, __shfl_xor(v, 4));
            v = fmaxf(v, __shfl_xor(v, 8));
            mt[r] = v;
        }
        #pragma unroll
        for (int r = 0; r < 4; ++r) {
            float mn = fmaxf(m[r], mt[r]);
            al[r] = __expf(m[r] - mn);
            m[r] = mn;
            rs[r] = 0.f;
        }
        #pragma unroll
        for (int cb = 0; cb < 4; ++cb) {
            #pragma unroll
            for (int r = 0; r < 4; ++r) {
                float p = __expf(s[cb][r] - m[r]);
                rs[r] += p;
                int row = g * 4 + r;
                int byte = row * 128 + (((cb * 16 + c) * 2) ^ ((row & 7) << 4));
                *(short*)(myP + byte) = f2bf(p);
            }
        }
        #pragma unroll
        for (int r = 0; r < 4; ++r) {
            float v = rs[r];
            v += __shfl_xor(v, 1);
            v += __shfl_xor(v, 2);
            v += __shfl_xor(v, 4);
            v += __shfl_xor(v, 8);
            l[r] = al[r] * l[r] + v;
        }
        f4v alv; alv[0] = al[0]; alv[1] = al[1]; alv[2] = al[2]; alv[3] = al[3];
        o0 *= alv; o1 *= alv; o2 *= alv; o3 *= alv;
        bh8 pa0 = *(const bh8*)(myP + c * 128 + (( 0 + g * 16) ^ ((c & 7) << 4)));
        bh8 pa1 = *(const bh8*)(myP + c * 128 + ((64 + g * 16) ^ ((c & 7) << 4)));
        #pragma unroll
        for (int db = 0; db < 4; ++db) {
            const short* vp = vbb + (size_t)(db * 16 + c) * NSEQ + k0;
            bh8 vb0 = *(const bh8*)(vp);
            bh8 vb1 = *(const bh8*)(vp + 32);
            f4v* op = (db == 0) ? &o0 : (db == 1) ? &o1 : (db == 2) ? &o2 : &o3;
            *op = __builtin_amdgcn_mfma_f32_16x16x32_bf16(pa0, vb0, *op, 0, 0, 0);
            *op = __builtin_amdgcn_mfma_f32_16x16x32_bf16(pa1, vb1, *op, 0, 0, 0);
        }
    }
    float linv[4];
    #pragma unroll
    for (int r = 0; r < 4; ++r) linv[r] = 1.f / l[r];
    #pragma unroll
    for (int r = 0; r < 4; ++r) {
        size_t rb = ((size_t)(b * NSEQ + q0 + g * 4 + r)) * 512 + h * 64 + c;
        ao[rb]      = f2bf(o0[r] * linv[r]);
        ao[rb + 16] = f2bf(o1[r] * linv[r]);
        ao[rb + 32] = f2bf(o2[r] * linv[r]);
        ao[rb + 48] = f2bf(o3[r] * linv[r]);
    }
}

// ---------- elementwise ----------
// GLU: h = val*sigmoid(gate); writes h f32, hg f32 copy, hi bf16, lo bf16 (split)
__global__ void glu_k(const float* __restrict__ vg, float* __restrict__ h, float* __restrict__ hgf,
                      short* __restrict__ hi, short* __restrict__ lo) {
    for (int i = blockIdx.x * 256 + threadIdx.x; i < ROWS * 512; i += gridDim.x * 256) {
        int row = i >> 9, c = i & 511;
        float v = vg[((size_t)row << 10) + c];
        float gt = vg[((size_t)row << 10) + 512 + c];
        float hv = v * (1.f / (1.f + expf(-gt)));
        h[i] = hv; hgf[i] = hv;
        short hb = f2bf(hv);
        hi[i] = hb;
        lo[i] = f2bf(hv - b2f(hb));
    }
}
__global__ void gelu_bf(const float* __restrict__ x, short* __restrict__ yb) {
    for (int i = blockIdx.x * 256 + threadIdx.x; i < ROWS * 1024; i += gridDim.x * 256) {
        float v = x[i];
        yb[i] = f2bf(0.5f * v * (1.f + erff(v * 0.70710678118654752f)));
    }
}
__global__ void tanh_k(float* __restrict__ x, int n) {
    for (int i = blockIdx.x * 256 + threadIdx.x; i < n; i += gridDim.x * 256)
        x[i] = tanhf(x[i]);
}
__global__ void concat_bf(const short* __restrict__ hgb, const short* __restrict__ htb,
                          short* __restrict__ cat) {
    for (int i = blockIdx.x * 256 + threadIdx.x; i < ROWS * 256; i += gridDim.x * 256) {
        int row = i >> 8, c4 = (i & 255) * 4;
        short4 v = (c4 < 512) ? *(const short4*)(hgb + ((size_t)row << 9) + c4)
                              : *(const short4*)(htb + ((size_t)row << 9) + c4 - 512);
        *(short4*)(cat + ((size_t)row << 10) + c4) = v;
    }
}
__global__ __launch_bounds__(256) void rowsq_k(const float* __restrict__ h, float* __restrict__ sq) {
    int row = blockIdx.x, tid = threadIdx.x;
    __shared__ float red[256];
    size_t base = (size_t)row << 9;
    float a = h[base + tid], b2 = h[base + tid + 256];
    float s = blockReduceSum(a * a + b2 * b2, red);
    if (tid == 0) sq[row] = s;
}

// ---------- pooling / classifier ----------
__global__ __launch_bounds__(256) void rowdot_k(const float* __restrict__ t, const float* __restrict__ w2,
                                                const float* __restrict__ b2, float* __restrict__ srow) {
    int row = blockIdx.x, tid = threadIdx.x;
    __shared__ float red[256];
    float s = blockReduceSum(t[(size_t)row * 256 + tid] * w2[tid], red);
    if (tid == 0) srow[row] = s + b2[0];
}
__global__ __launch_bounds__(256) void softmax_n_k(const float* __restrict__ srow, float* __restrict__ a,
                                                   float* __restrict__ out) {
    int b = blockIdx.x, tid = threadIdx.x;
    __shared__ float red[256];
    float mx = -INFINITY;
    for (int n = tid; n < NSEQ; n += 256) mx = fmaxf(mx, srow[b * NSEQ + n]);
    red[tid] = mx; __syncthreads();
    for (int s = 128; s > 0; s >>= 1) {
        if (tid < s) red[tid] = fmaxf(red[tid], red[tid + s]);
        __syncthreads();
    }
    mx = red[0]; __syncthreads();
    float sm = 0.f;
    for (int n = tid; n < NSEQ; n += 256) {
        float e = expf(srow[b * NSEQ + n] - mx);
        a[b * NSEQ + n] = e; sm += e;
    }
    float inv = 1.f / blockReduceSum(sm, red);
    for (int n = tid; n < NSEQ; n += 256) {
        float v = a[b * NSEQ + n] * inv;
        a[b * NSEQ + n] = v;
        out[2 + b * NSEQ + n] = v;
    }
}
__global__ __launch_bounds__(256) void pool_part(const float* __restrict__ hf, const float* __restrict__ a,
                                                 float* __restrict__ part) {
    int b = blockIdx.y, chunk = blockIdx.x, tid = threadIdx.x;
    float a0 = 0.f, a1 = 0.f;
    for (int r = 0; r < 64; ++r) {
        int n = chunk * 64 + r;
        float wgt = a[b * NSEQ + n];
        const float* row = hf + ((size_t)(b * NSEQ + n) << 9);
        a0 = fmaf(row[tid], wgt, a0);
        a1 = fmaf(row[tid + 256], wgt, a1);
    }
    part[((b * 32 + chunk) << 9) + tid] = a0;
    part[((b * 32 + chunk) << 9) + tid + 256] = a1;
}
__global__ __launch_bounds__(256) void pool_fin(const float* __restrict__ part, float* __restrict__ Mb,
                                                float* __restrict__ out) {
    int b = blockIdx.x, tid = threadIdx.x;
    float s0 = 0.f, s1 = 0.f;
    for (int ch = 0; ch < 32; ++ch) {
        s0 += part[((b * 32 + ch) << 9) + tid];
        s1 += part[((b * 32 + ch) << 9) + tid + 256];
    }
    Mb[b * 512 + tid] = s0; Mb[b * 512 + tid + 256] = s1;
    out[2 + ROWS + b * 512 + tid] = s0; out[2 + ROWS + b * 512 + tid + 256] = s1;
}
__global__ __launch_bounds__(256) void classifier_k(const float* __restrict__ Mb,
        const float* __restrict__ w1, const float* __restrict__ b1,
        const float* __restrict__ w2, const float* __restrict__ b2, float* __restrict__ out) {
    int b = blockIdx.x, tid = threadIdx.x;
    __shared__ float Ms[512];
    __shared__ float red[256];
    for (int c = tid; c < 512; c += 256) Ms[c] = Mb[b * 512 + c];
    __syncthreads();
    float acc = 0.f;
    for (int c = 0; c < 512; ++c) acc = fmaf(Ms[c], w1[tid * 512 + c], acc);
    acc += b1[tid];
    float hj = acc > 0.f ? acc : expm1f(acc);   // ELU alpha=1
    float s = blockReduceSum(hj * w2[tid], red);
    if (tid == 0) out[b] = s + b2[0];
}

extern "C" void kernel_launch(void* const* d_in, const int* in_sizes, int n_in,
                              void* d_out, int out_size, void* d_ws, size_t ws_size,
                              hipStream_t stream)
{
    const float* X      = (const float*)d_in[0];
    const float* Wstart = (const float*)d_in[1];
    const float* Bstart = (const float*)d_in[2];
    const float* GluW   = (const float*)d_in[3];
    const float* GluB   = (const float*)d_in[4];
    const float* GcnW   = (const float*)d_in[5];
    const float* GcnB   = (const float*)d_in[6];
    const float* GcnG   = (const float*)d_in[7];
    const float* GcnBe  = (const float*)d_in[8];
    const float* QkvW   = (const float*)d_in[9];
    const float* QkvB   = (const float*)d_in[10];
    const float* OutW   = (const float*)d_in[11];
    const float* OutB   = (const float*)d_in[12];
    const float* Ln1G   = (const float*)d_in[13];
    const float* Ln1B   = (const float*)d_in[14];
    const float* Ffn1W  = (const float*)d_in[15];
    const float* Ffn1B  = (const float*)d_in[16];
    const float* Ffn2W  = (const float*)d_in[17];
    const float* Ffn2B  = (const float*)d_in[18];
    const float* Ln2G   = (const float*)d_in[19];
    const float* Ln2B   = (const float*)d_in[20];
    const float* FusW   = (const float*)d_in[21];
    const float* FusB   = (const float*)d_in[22];
    const float* AW1    = (const float*)d_in[23];
    const float* AB1    = (const float*)d_in[24];
    const float* AW2    = (const float*)d_in[25];
    const float* AB2    = (const float*)d_in[26];
    const float* CW1    = (const float*)d_in[27];
    const float* CB1    = (const float*)d_in[28];
    const float* CW2    = (const float*)d_in[29];
    const float* CB2    = (const float*)d_in[30];
    float* out = (float*)d_out;

    if (ws_size < 87 * MB) return;  // layout needs 86MB

    char* w = (char*)d_ws;
    // bf16 weight arena [0,13MB)
    short* Wb = (short*)w;
    short* wbStart = Wb;                 // 524288
    short* wbGlu   = Wb + 524288;        // 524288
    short* wbGcn   = Wb + 1048576;       // 524288 (2 layers)
    short* wbQkv   = Wb + 1572864;       // 1572864 (2 layers)
    short* wbOut   = Wb + 3145728;       // 524288
    short* wbFfn1  = Wb + 3670016;       // 1048576
    short* wbFfn2  = Wb + 4718592;       // 1048576
    short* wbFus   = Wb + 5767168;       // 524288
    short* wbAw1   = Wb + 6291456;       // 131072
    // small [13MB,14MB)
    float* sq   = (float*)(w + 13 * MB);
    int*   idx  = (int*)  (w + 13 * MB + (16u << 10));
    float* srow = (float*)(w + 13 * MB + (176u << 10));
    float* afb  = (float*)(w + 13 * MB + (192u << 10));
    float* Mbuf = (float*)(w + 13 * MB + (208u << 10));
    float* part = (float*)(w + 13 * MB + (212u << 10));
    // overlapped big buffers
    short* Xbf  = (short*)(w + 14 * MB);   // 8MB, dead after gemm1
    float* hg   = (float*)(w + 14 * MB);   // 8MB f32 (after gemm1)
    short* hpreb= (short*)(w + 22 * MB);   // 4MB, dead after GLU gemm
    short* hgb  = (short*)(w + 22 * MB);   // 4MB bf16 (after GLU gemm)
    float* big  = (float*)(w + 26 * MB);   // 24MB: vg/d2/qkv/ff/s/attn_out
    float* ffn2o= (float*)(w + 42 * MB);   // 8MB (inside big upper half)
    float* h    = (float*)(w + 50 * MB);   // 8MB f32; doubles as ht
    short* hhi  = (short*)(w + 58 * MB);   // 4MB; later Qb; later hf low half
    short* hlo  = (short*)(w + 62 * MB);   // 4MB; later Kb; later hf high half
    short* Qb   = (short*)(w + 58 * MB);
    short* Kb   = (short*)(w + 62 * MB);
    float* hf   = (float*)(w + 58 * MB);   // 8MB (after attention)
    short* Vt   = (short*)(w + 66 * MB);   // 4MB; later hfb
    short* hfb  = (short*)(w + 66 * MB);
    short* aob  = (short*)(w + 70 * MB);   // 4MB; later t256
    float* t256 = (float*)(w + 70 * MB);
    short* ffb  = (short*)(w + 74 * MB);   // 8MB; later catb
    short* catb = (short*)(w + 74 * MB);
    short* htb  = (short*)(w + 82 * MB);   // 4MB

    dim3 blk(256);

    // convert X + all GEMM weights to bf16
    CvtArgs ca;
    ca.src[0] = X;     ca.dst[0] = Xbf;     ca.n4[0] = ROWS * 1024 / 4;
    ca.src[1] = Wstart;ca.dst[1] = wbStart; ca.n4[1] = 524288 / 4;
    ca.src[2] = GluW;  ca.dst[2] = wbGlu;   ca.n4[2] = 524288 / 4;
    ca.src[3] = GcnW;  ca.dst[3] = wbGcn;   ca.n4[3] = 524288 / 4;
    ca.src[4] = QkvW;  ca.dst[4] = wbQkv;   ca.n4[4] = 1572864 / 4;
    ca.src[5] = OutW;  ca.dst[5] = wbOut;   ca.n4[5] = 524288 / 4;
    ca.src[6] = Ffn1W; ca.dst[6] = wbFfn1;  ca.n4[6] = 1048576 / 4;
    ca.src[7] = Ffn2W; ca.dst[7] = wbFfn2;  ca.n4[7] = 1048576 / 4;
    ca.src[8] = FusW;  ca.dst[8] = wbFus;   ca.n4[8] = 524288 / 4;
    ca.src[9] = AW1;   ca.dst[9] = wbAw1;   ca.n4[9] = 131072 / 4;
    cvt_k<<<dim3(256, 10), blk, 0, stream>>>(ca);

    // fc_start -> GLU
    mfma_gemm<1><<<dim3(4, 32), blk, 0, stream>>>(Xbf, wbStart, Bstart, nullptr, hpreb, ROWS, 512, 1024);
    mfma_gemm<0><<<dim3(8, 32), blk, 0, stream>>>(hpreb, wbGlu, GluB, big, nullptr, ROWS, 1024, 512);
    glu_k<<<dim3(2048), blk, 0, stream>>>(big, h, hg, hhi, hlo);
    rowsq_k<<<dim3(ROWS), blk, 0, stream>>>(h, sq);

    // KNN graph (hi/lo split gram, f32-equivalent ranking)
    for (int b = 0; b < 2; ++b) {
        mfma_gram<<<dim3(16, 16), blk, 0, stream>>>(hhi + (size_t)b * NSEQ * 512,
                                                    hlo + (size_t)b * NSEQ * 512,
                                                    sq + b * NSEQ, big);
        topk9_k<<<dim3(NSEQ), blk, 0, stream>>>(big, idx + b * NSEQ * KNN);
    }

    // GCN branch
    const short* gA = hhi;
    for (int i = 0; i < 2; ++i) {
        mfma_gemm<0><<<dim3(4, 32), blk, 0, stream>>>(gA, wbGcn + (size_t)i * 262144,
                                                      GcnB + i * 512, big, nullptr, ROWS, 512, 512);
        gcn_post<<<dim3(ROWS), blk, 0, stream>>>(big, idx, GcnG + i * 512, GcnBe + i * 512, hg, hgb);
        gA = hgb;
    }

    // Transformer branch (h doubles as ht)
    const short* tA = hhi;
    for (int i = 0; i < 2; ++i) {
        mfma_gemm<0><<<dim3(12, 32), blk, 0, stream>>>(tA, wbQkv + (size_t)i * 786432,
                                                       QkvB + i * 1536, big, nullptr, ROWS, 1536, 512);
        qk_convert<<<dim3(2048), blk, 0, stream>>>(big, Qb, Kb);
        vt_convert<<<dim3(32, 8, 2), blk, 0, stream>>>(big, Vt);
        flash_attn<<<dim3(32, 8, 2), blk, 0, stream>>>(Qb, Kb, Vt, aob);
        mfma_gemm<0><<<dim3(4, 32), blk, 0, stream>>>(aob, wbOut + (size_t)i * 262144,
                                                      OutB + i * 512, big, nullptr, ROWS, 512, 512);
        ln_res<<<dim3(ROWS), blk, 0, stream>>>(h, big, Ln1G + i * 512, Ln1B + i * 512, htb);
        mfma_gemm<0><<<dim3(8, 32), blk, 0, stream>>>(htb, wbFfn1 + (size_t)i * 524288,
                                                      Ffn1B + i * 1024, big, nullptr, ROWS, 1024, 512);
        gelu_bf<<<dim3(2048), blk, 0, stream>>>(big, ffb);
        mfma_gemm<0><<<dim3(4, 32), blk, 0, stream>>>(ffb, wbFfn2 + (size_t)i * 524288,
                                                      Ffn2B + i * 512, ffn2o, nullptr, ROWS, 512, 1024);
        ln_res<<<dim3(ROWS), blk, 0, stream>>>(h, ffn2o, Ln2G + i * 512, Ln2B + i * 512, htb);
        tA = htb;
    }

    // fusion
    concat_bf<<<dim3(2048), blk, 0, stream>>>(hgb, htb, catb);
    mfma_gemm<2><<<dim3(4, 32), blk, 0, stream>>>(catb, wbFus, FusB, hf, hfb, ROWS, 512, 1024);

    // gated attention pooling
    mfma_gemm<0><<<dim3(2, 32), blk, 0, stream>>>(hfb, wbAw1, AB1, t256, nullptr, ROWS, 256, 512);
    tanh_k<<<dim3(1024), blk, 0, stream>>>(t256, ROWS * 256);
    rowdot_k<<<dim3(ROWS), blk, 0, stream>>>(t256, AW2, AB2, srow);
    softmax_n_k<<<dim3(2), blk, 0, stream>>>(srow, afb, out);
    pool_part<<<dim3(32, 2), blk, 0, stream>>>(hf, afb, part);
    pool_fin<<<dim3(2), blk, 0, stream>>>(part, Mbuf, out);

    // classifier
    classifier_k<<<dim3(2), blk, 0, stream>>>(Mbuf, CW1, CB1, CW2, CB2, out);
}

// Round 6
// 682.753 us; speedup vs baseline: 10.1587x; 1.0910x over previous
//
#include <hip/hip_runtime.h>
#include <hip/hip_bf16.h>
#include <math.h>

#define NSEQ 2048
#define ROWS 4096   // B*N
#define KNN 9
#define MB (1ull << 20)

typedef short bh8 __attribute__((ext_vector_type(8)));   // 8 bf16 in 4 VGPRs
typedef float f4v __attribute__((ext_vector_type(4)));

__device__ __forceinline__ short f2bf(float f) {
    union { float f; unsigned u; } v; v.f = f;
    unsigned r = (v.u + 0x7fffu + ((v.u >> 16) & 1u)) >> 16;
    return (short)r;
}
__device__ __forceinline__ float b2f(short s) {
    union { unsigned u; float f; } v; v.u = ((unsigned)(unsigned short)s) << 16; return v.f;
}

// async global->LDS, 16B per lane; LDS dest is wave-uniform base + lane*16
__device__ __forceinline__ void gload16(const void* g, void* l) {
    __builtin_amdgcn_global_load_lds(
        (const __attribute__((address_space(1))) void*)g,
        (__attribute__((address_space(3))) void*)l, 16, 0, 0);
}

// ---------- block reduce (blockDim.x == 256) ----------
__device__ __forceinline__ float blockReduceSum(float v, float* red) {
    int tid = threadIdx.x;
    red[tid] = v; __syncthreads();
    for (int s = 128; s > 0; s >>= 1) {
        if (tid < s) red[tid] += red[tid + s];
        __syncthreads();
    }
    float r = red[0]; __syncthreads();
    return r;
}

// ---------- f32 -> bf16 conversion (weights + X), 10 segments ----------
struct CvtArgs { const float* src[10]; short* dst[10]; int n4[10]; };
__global__ __launch_bounds__(256) void cvt_k(CvtArgs a) {
    int s = blockIdx.y;
    const float* sp = a.src[s]; short* dp = a.dst[s]; int n = a.n4[s];
    for (int i = blockIdx.x * 256 + threadIdx.x; i < n; i += gridDim.x * 256) {
        float4 v = ((const float4*)sp)[i];
        short4 o; o.x = f2bf(v.x); o.y = f2bf(v.y); o.z = f2bf(v.z); o.w = f2bf(v.w);
        ((short4*)dp)[i] = o;
    }
}

// ---------- MFMA GEMM: C[M,N] = A[M,K](bf16) @ W[N,K](bf16)^T + bias ----------
// BM x 128 tile, BK=64. BM=128: 4 waves 2x2; BM=64: 2 waves 1x2. Wave tile 64x64.
// OUTMODE: 0=f32, 1=bf16, 2=both, 3=qkv special (Q*0.125/K/V head-major bf16;
//          K at Cb+4MB, V at Cb+8MB), 4=gelu->bf16, 5=tanh->f32
template <int BM, int OUTMODE>
__global__ __launch_bounds__((BM / 32) * 64) void mfma_gemm(
        const short* __restrict__ A, const short* __restrict__ W,
        const float* __restrict__ bias, float* __restrict__ Cf, short* __restrict__ Cb,
        int M, int N, int K)
{
    constexpr int NW = BM / 32;           // waves per block
    __shared__ short As[BM * 64];
    __shared__ short Bs[128 * 64];
    int tid = threadIdx.x;
    int wv = tid >> 6, l = tid & 63;
    int g = l >> 4, c = l & 15;
    int wr = wv >> 1, wc = wv & 1;        // BM=64: wr==0
    int bm = blockIdx.y * BM, bn = blockIdx.x * 128;
    int sr = l >> 3, sc = (l & 7) * 8;
    const short* Ap = A + (size_t)(bm + wv * 32 + sr) * K + sc;
    const short* Wp = W + (size_t)(bn + wv * (128 / NW) + sr) * K + sc;
    short* AsB = As + (wv * 32) * 64;
    short* BsB = Bs + (wv * (128 / NW)) * 64;
    f4v acc[4][4] = {};
    for (int k0 = 0; k0 < K; k0 += 64) {
        __syncthreads();
        #pragma unroll
        for (int j = 0; j < 4; ++j)
            gload16(Ap + (size_t)(j * 8) * K + k0, AsB + j * 8 * 64);
        #pragma unroll
        for (int j = 0; j < 128 / NW / 8; ++j)
            gload16(Wp + (size_t)(j * 8) * K + k0, BsB + j * 8 * 64);
        __syncthreads();
        #pragma unroll
        for (int ks = 0; ks < 2; ++ks) {
            bh8 af[4], bf_[4];
            #pragma unroll
            for (int mi = 0; mi < 4; ++mi)
                af[mi] = *(const bh8*)(As + (wr * 64 + mi * 16 + c) * 64 + ks * 32 + g * 8);
            #pragma unroll
            for (int ni = 0; ni < 4; ++ni)
                bf_[ni] = *(const bh8*)(Bs + (wc * 64 + ni * 16 + c) * 64 + ks * 32 + g * 8);
            #pragma unroll
            for (int mi = 0; mi < 4; ++mi)
                #pragma unroll
                for (int ni = 0; ni < 4; ++ni)
                    acc[mi][ni] = __builtin_amdgcn_mfma_f32_16x16x32_bf16(af[mi], bf_[ni], acc[mi][ni], 0, 0, 0);
        }
    }
    short* Kb_  = (OUTMODE == 3) ? Cb + 2097152 : nullptr;   // +4MB
    short* Vt_  = (OUTMODE == 3) ? Cb + 4194304 : nullptr;   // +8MB
    #pragma unroll
    for (int mi = 0; mi < 4; ++mi) {
        int row = bm + wr * 64 + mi * 16 + g * 4;
        #pragma unroll
        for (int ni = 0; ni < 4; ++ni) {
            int col = bn + wc * 64 + ni * 16 + c;
            float bv = bias[col];
            #pragma unroll
            for (int rr = 0; rr < 4; ++rr) {
                float v = acc[mi][ni][rr] + bv;
                if (OUTMODE == 0) Cf[(size_t)(row + rr) * N + col] = v;
                else if (OUTMODE == 1) Cb[(size_t)(row + rr) * N + col] = f2bf(v);
                else if (OUTMODE == 2) {
                    Cf[(size_t)(row + rr) * N + col] = v;
                    Cb[(size_t)(row + rr) * N + col] = f2bf(v);
                } else if (OUTMODE == 3) {
                    int b = (row + rr) >> 11, n = (row + rr) & 2047;
                    if (col < 512) {
                        int h = col >> 6, d = col & 63;
                        Cb[(((size_t)(b * 8 + h) * NSEQ + n) << 6) + d] = f2bf(v * 0.125f);
                    } else if (col < 1024) {
                        int cc = col - 512, h = cc >> 6, d = cc & 63;
                        Kb_[(((size_t)(b * 8 + h) * NSEQ + n) << 6) + d] = f2bf(v);
                    } else {
                        int cc = col - 1024, h = cc >> 6, d = cc & 63;
                        Vt_[(((size_t)(b * 8 + h) * NSEQ + n) << 6) + d] = f2bf(v);
                    }
                } else if (OUTMODE == 4) {
                    Cb[(size_t)(row + rr) * N + col] = f2bf(0.5f * v * (1.f + erff(v * 0.70710678118654752f)));
                } else if (OUTMODE == 5) {
                    Cf[(size_t)(row + rr) * N + col] = tanhf(v);
                }
            }
        }
    }
}

// ---------- gram for KNN distances, hi/lo split (f32-equivalent precision) ----------
__global__ __launch_bounds__(256) void mfma_gram(
        const short* __restrict__ Hi, const short* __restrict__ Lo,
        const float* __restrict__ SQ, float* __restrict__ D2)
{
    __shared__ short HiR[128 * 64], LoR[128 * 64], HiC[128 * 64], LoC[128 * 64];
    int tid = threadIdx.x;
    int wv = tid >> 6, l = tid & 63;
    int g = l >> 4, c = l & 15;
    int wr = wv >> 1, wc = wv & 1;
    int bm = blockIdx.y * 128, bn = blockIdx.x * 128;
    int srowo = wv * 32 + (l >> 3);
    int scol = (l & 7) * 8;
    const short* hiR = Hi + (size_t)(bm + srowo) * 512 + scol;
    const short* loR = Lo + (size_t)(bm + srowo) * 512 + scol;
    const short* hiC = Hi + (size_t)(bn + srowo) * 512 + scol;
    const short* loC = Lo + (size_t)(bn + srowo) * 512 + scol;
    int ldsOff = (wv * 32) * 64;
    f4v acc[4][4] = {};
    for (int k0 = 0; k0 < 512; k0 += 64) {
        __syncthreads();
        #pragma unroll
        for (int j = 0; j < 4; ++j) {
            gload16(hiR + (size_t)(j * 8) * 512 + k0, HiR + ldsOff + j * 8 * 64);
            gload16(loR + (size_t)(j * 8) * 512 + k0, LoR + ldsOff + j * 8 * 64);
            gload16(hiC + (size_t)(j * 8) * 512 + k0, HiC + ldsOff + j * 8 * 64);
            gload16(loC + (size_t)(j * 8) * 512 + k0, LoC + ldsOff + j * 8 * 64);
        }
        __syncthreads();
        #pragma unroll
        for (int ks = 0; ks < 2; ++ks) {
            bh8 hr[4], lr_[4], hc[4], lc[4];
            #pragma unroll
            for (int mi = 0; mi < 4; ++mi) {
                int o = (wr * 64 + mi * 16 + c) * 64 + ks * 32 + g * 8;
                hr[mi] = *(const bh8*)(HiR + o);
                lr_[mi] = *(const bh8*)(LoR + o);
            }
            #pragma unroll
            for (int ni = 0; ni < 4; ++ni) {
                int o = (wc * 64 + ni * 16 + c) * 64 + ks * 32 + g * 8;
                hc[ni] = *(const bh8*)(HiC + o);
                lc[ni] = *(const bh8*)(LoC + o);
            }
            #pragma unroll
            for (int mi = 0; mi < 4; ++mi)
                #pragma unroll
                for (int ni = 0; ni < 4; ++ni) {
                    acc[mi][ni] = __builtin_amdgcn_mfma_f32_16x16x32_bf16(hr[mi], hc[ni], acc[mi][ni], 0, 0, 0);
                    acc[mi][ni] = __builtin_amdgcn_mfma_f32_16x16x32_bf16(hr[mi], lc[ni], acc[mi][ni], 0, 0, 0);
                    acc[mi][ni] = __builtin_amdgcn_mfma_f32_16x16x32_bf16(lr_[mi], hc[ni], acc[mi][ni], 0, 0, 0);
                }
        }
    }
    #pragma unroll
    for (int mi = 0; mi < 4; ++mi) {
        int row = bm + wr * 64 + mi * 16 + g * 4;
        #pragma unroll
        for (int ni = 0; ni < 4; ++ni) {
            int col = bn + wc * 64 + ni * 16 + c;
            float sqc = SQ[col];
            #pragma unroll
            for (int rr = 0; rr < 4; ++rr)
                D2[(size_t)(row + rr) * NSEQ + col] = SQ[row + rr] + sqc - 2.f * acc[mi][ni][rr];
        }
    }
}

// ---------- top-9 smallest per row ----------
__global__ __launch_bounds__(256) void topk9_k(const float* __restrict__ D2, int* __restrict__ idx)
{
    int n = blockIdx.x, tid = threadIdx.x;
    __shared__ float vals[NSEQ];
    __shared__ float rv[256];
    __shared__ int   ri[256];
    for (int m = tid; m < NSEQ; m += 256)
        vals[m] = fmaxf(D2[(size_t)n * NSEQ + m], 0.f);
    __syncthreads();
    for (int it = 0; it < KNN; ++it) {
        float bv = INFINITY; int bi = 0x7fffffff;
        #pragma unroll
        for (int j = 0; j < 8; ++j) {
            int m = tid + j * 256;
            float v = vals[m];
            if (v < bv) { bv = v; bi = m; }
        }
        rv[tid] = bv; ri[tid] = bi; __syncthreads();
        for (int s = 128; s > 0; s >>= 1) {
            if (tid < s) {
                if (rv[tid + s] < rv[tid] || (rv[tid + s] == rv[tid] && ri[tid + s] < ri[tid])) {
                    rv[tid] = rv[tid + s]; ri[tid] = ri[tid + s];
                }
            }
            __syncthreads();
        }
        int win = ri[0];
        if (tid == 0) { idx[n * KNN + it] = win; vals[win] = INFINITY; }
        __syncthreads();
    }
}

// ---------- GCN aggregate + LN + leaky + residual (writes f32 + bf16) ----------
__global__ __launch_bounds__(256) void gcn_post(
        const float* __restrict__ s, const int* __restrict__ idx,
        const float* __restrict__ g, const float* __restrict__ be,
        float* __restrict__ hg, short* __restrict__ hgb)
{
    int row = blockIdx.x, tid = threadIdx.x;
    int bb = row >> 11;
    __shared__ float os[512];
    __shared__ float red[256];
    int id[KNN];
    #pragma unroll
    for (int j = 0; j < KNN; ++j) id[j] = idx[row * KNN + j] + (bb << 11);
    for (int c = tid; c < 512; c += 256) {
        float acc = 0.f;
        #pragma unroll
        for (int j = 0; j < KNN; ++j) acc += s[((size_t)id[j] << 9) + c];
        os[c] = acc * (1.f / 9.f);
    }
    __syncthreads();
    float mean = blockReduceSum(os[tid] + os[tid + 256], red) * (1.f / 512.f);
    float d0 = os[tid] - mean, d1 = os[tid + 256] - mean;
    float var = blockReduceSum(d0 * d0 + d1 * d1, red) * (1.f / 512.f);
    float rs = rsqrtf(var + 1e-5f);
    size_t base = (size_t)row << 9;
    for (int c = tid; c < 512; c += 256) {
        float y = (os[c] - mean) * rs * g[c] + be[c];
        y = y > 0.f ? y : 0.2f * y;
        float nv = y + hg[base + c];
        hg[base + c] = nv;
        hgb[base + c] = f2bf(nv);
    }
}

// ---------- x = LN(x + r)*g + b (writes f32 + bf16) ----------
__global__ __launch_bounds__(256) void ln_res(
        float* __restrict__ x, const float* __restrict__ r,
        const float* __restrict__ g, const float* __restrict__ b, short* __restrict__ xb)
{
    int row = blockIdx.x, tid = threadIdx.x;
    __shared__ float xs[512];
    __shared__ float red[256];
    size_t base = (size_t)row << 9;
    for (int c = tid; c < 512; c += 256) xs[c] = x[base + c] + r[base + c];
    __syncthreads();
    float mean = blockReduceSum(xs[tid] + xs[tid + 256], red) * (1.f / 512.f);
    float d0 = xs[tid] - mean, d1 = xs[tid + 256] - mean;
    float var = blockReduceSum(d0 * d0 + d1 * d1, red) * (1.f / 512.f);
    float rs = rsqrtf(var + 1e-5f);
    for (int c = tid; c < 512; c += 256) {
        float y = (xs[c] - mean) * rs * g[c] + b[c];
        x[base + c] = y;
        xb[base + c] = f2bf(y);
    }
}

// ---------- V [bh][n][64] -> Vt [bh][64][2048] (bf16 transpose) ----------
__global__ __launch_bounds__(256) void vtr_k(const short* __restrict__ Vtmp, short* __restrict__ Vt)
{
    int nt = blockIdx.x, bh = blockIdx.y;
    int t = threadIdx.x;
    #pragma unroll
    for (int it = 0; it < 2; ++it) {
        int idx = it * 256 + t;
        int d = idx >> 3, nc = (idx & 7) * 8;
        short tmp[8];
        #pragma unroll
        for (int j = 0; j < 8; ++j)
            tmp[j] = Vtmp[(((size_t)bh * NSEQ + nt * 64 + nc + j) << 6) + d];
        *(bh8*)(Vt + (((size_t)bh * 64 + d) << 11) + nt * 64 + nc) = *(const bh8*)tmp;
    }
}

// ---------- flash attention: LDS-staged K/V, KV-split=2, partials out ----------
__global__ __launch_bounds__(256) void flash_attn(
        const short* __restrict__ Qb, const short* __restrict__ Kb,
        const short* __restrict__ Vt, float* __restrict__ Op, float* __restrict__ Ml)
{
    __shared__ short Ks[2][4096];
    __shared__ short Vs[2][4096];
    __shared__ char Pl[4][2048];
    int tid = threadIdx.x;
    int wid = tid >> 6, lane = tid & 63;
    int g = lane >> 4, c = lane & 15;
    int s = blockIdx.y, bh = blockIdx.z;
    int q0 = blockIdx.x * 64 + wid * 16;
    char* myP = Pl[wid];
    int srow = lane >> 3;                  // 0..7
    int sc8 = ((lane & 7) ^ srow) * 8;     // pre-swizzled source chunk (involution)
    int w8 = wid * 8;

    const short* KbB = Kb + ((size_t)bh * NSEQ + s * (NSEQ / 2)) * 64;
    const short* VtB = Vt + (size_t)bh * 64 * NSEQ + s * (NSEQ / 2);

    const short* qbase = Qb + ((size_t)bh * NSEQ + q0 + c) * 64 + g * 8;
    bh8 qa0 = *(const bh8*)(qbase);
    bh8 qa1 = *(const bh8*)(qbase + 32);

    f4v o0 = {0,0,0,0}, o1 = {0,0,0,0}, o2 = {0,0,0,0}, o3 = {0,0,0,0};
    float m[4] = {-INFINITY,-INFINITY,-INFINITY,-INFINITY};
    float l[4] = {0,0,0,0};

    #define FSTAGE(buf, kt) { \
        const short* kp_ = KbB + (size_t)(kt) * 64 * 64; \
        gload16(kp_ + (size_t)(w8 + srow) * 64 + sc8,        &Ks[buf][w8 * 64]); \
        gload16(kp_ + (size_t)(32 + w8 + srow) * 64 + sc8,   &Ks[buf][(32 + w8) * 64]); \
        const short* vp_ = VtB + (size_t)(kt) * 64; \
        gload16(vp_ + (size_t)(w8 + srow) * NSEQ + sc8,      &Vs[buf][w8 * 64]); \
        gload16(vp_ + (size_t)(32 + w8 + srow) * NSEQ + sc8, &Vs[buf][(32 + w8) * 64]); }

    FSTAGE(0, 0);
    __syncthreads();
    for (int t = 0; t < 16; ++t) {
        int cur = t & 1;
        if (t < 15) FSTAGE(cur ^ 1, t + 1);
        // ---- QK^T from swizzled LDS ----
        f4v sv[4];
        #pragma unroll
        for (int cb = 0; cb < 4; ++cb) {
            int row = cb * 16 + c;
            const short* kr = &Ks[cur][row * 64];
            bh8 kb0 = *(const bh8*)(kr + ((g ^ (row & 7)) * 8));
            bh8 kb1 = *(const bh8*)(kr + (((4 + g) ^ (row & 7)) * 8));
            f4v a = {0,0,0,0};
            a = __builtin_amdgcn_mfma_f32_16x16x32_bf16(qa0, kb0, a, 0, 0, 0);
            a = __builtin_amdgcn_mfma_f32_16x16x32_bf16(qa1, kb1, a, 0, 0, 0);
            sv[cb] = a;
        }
        // ---- online softmax ----
        float mt[4], rs[4], al[4];
        #pragma unroll
        for (int r = 0; r < 4; ++r) {
            float v = fmaxf(fmaxf(sv[0][r], sv[1][r]), fmaxf(sv[2][r], sv[3][r]));
            v = fmaxf(v, __shfl_xor(v, 1));
            v = fmaxf(v, __shfl_xor(v, 2));
            v = fmaxf(v, __shfl_xor(v, 4));
            v = fmaxf(v, __shfl_xor(v, 8));
            mt[r] = v;
        }
        #pragma unroll
        for (int r = 0; r < 4; ++r) {
            float mn = fmaxf(m[r], mt[r]);
            al[r] = __expf(m[r] - mn);
            m[r] = mn;
            rs[r] = 0.f;
        }
        #pragma unroll
        for (int cb = 0; cb < 4; ++cb) {
            #pragma unroll
            for (int r = 0; r < 4; ++r) {
                float p = __expf(sv[cb][r] - m[r]);
                rs[r] += p;
                int row = g * 4 + r;
                int byte = row * 128 + (((cb * 16 + c) * 2) ^ ((row & 7) << 4));
                *(short*)(myP + byte) = f2bf(p);
            }
        }
        #pragma unroll
        for (int r = 0; r < 4; ++r) {
            float v = rs[r];
            v += __shfl_xor(v, 1);
            v += __shfl_xor(v, 2);
            v += __shfl_xor(v, 4);
            v += __shfl_xor(v, 8);
            l[r] = al[r] * l[r] + v;
        }
        f4v alv; alv[0] = al[0]; alv[1] = al[1]; alv[2] = al[2]; alv[3] = al[3];
        o0 *= alv; o1 *= alv; o2 *= alv; o3 *= alv;
        // ---- PV from wave-private P + swizzled V LDS ----
        bh8 pa0 = *(const bh8*)(myP + c * 128 + (( 0 + g * 16) ^ ((c & 7) << 4)));
        bh8 pa1 = *(const bh8*)(myP + c * 128 + ((64 + g * 16) ^ ((c & 7) << 4)));
        #pragma unroll
        for (int db = 0; db < 4; ++db) {
            int row = db * 16 + c;
            const short* vr = &Vs[cur][row * 64];
            bh8 vb0 = *(const bh8*)(vr + ((g ^ (row & 7)) * 8));
            bh8 vb1 = *(const bh8*)(vr + (((4 + g) ^ (row & 7)) * 8));
            f4v* op = (db == 0) ? &o0 : (db == 1) ? &o1 : (db == 2) ? &o2 : &o3;
            *op = __builtin_amdgcn_mfma_f32_16x16x32_bf16(pa0, vb0, *op, 0, 0, 0);
            *op = __builtin_amdgcn_mfma_f32_16x16x32_bf16(pa1, vb1, *op, 0, 0, 0);
        }
        __syncthreads();
    }
    #undef FSTAGE
    #pragma unroll
    for (int r = 0; r < 4; ++r) {
        size_t rb = (((size_t)(s * 16 + bh) * NSEQ) + q0 + g * 4 + r) * 64 + c;
        Op[rb]      = o0[r];
        Op[rb + 16] = o1[r];
        Op[rb + 32] = o2[r];
        Op[rb + 48] = o3[r];
    }
    if (c == 0) {
        #pragma unroll
        for (int r = 0; r < 4; ++r) {
            size_t mb = (((size_t)(s * 16 + bh) * NSEQ) + q0 + g * 4 + r) * 2;
            Ml[mb] = m[r]; Ml[mb + 1] = l[r];
        }
    }
}

// ---------- merge 2 KV-splits -> bf16 attention output ----------
__global__ __launch_bounds__(256) void merge_k(const float* __restrict__ Op, const float* __restrict__ Ml,
                                               short* __restrict__ aob)
{
    int idx = blockIdx.x * 256 + threadIdx.x;   // 16*2048*64
    int d = idx & 63, q = (idx >> 6) & 2047, bh = idx >> 17;
    size_t r0 = (size_t)bh * NSEQ + q;
    size_t r1 = (size_t)(16 + bh) * NSEQ + q;
    float m0 = Ml[r0 * 2], l0 = Ml[r0 * 2 + 1];
    float m1 = Ml[r1 * 2], l1 = Ml[r1 * 2 + 1];
    float M = fmaxf(m0, m1);
    float w0 = __expf(m0 - M), w1 = __expf(m1 - M);
    float L = l0 * w0 + l1 * w1;
    float v = (Op[r0 * 64 + d] * w0 + Op[r1 * 64 + d] * w1) / L;
    int b = bh >> 3, h = bh & 7;
    aob[((size_t)(b * NSEQ + q)) * 512 + h * 64 + d] = f2bf(v);
}

// ---------- elementwise ----------
__global__ void glu_k(const float* __restrict__ vg, float* __restrict__ h, float* __restrict__ hgf,
                      short* __restrict__ hi, short* __restrict__ lo) {
    for (int i = blockIdx.x * 256 + threadIdx.x; i < ROWS * 512; i += gridDim.x * 256) {
        int row = i >> 9, c = i & 511;
        float v = vg[((size_t)row << 10) + c];
        float gt = vg[((size_t)row << 10) + 512 + c];
        float hv = v * (1.f / (1.f + expf(-gt)));
        h[i] = hv; hgf[i] = hv;
        short hb = f2bf(hv);
        hi[i] = hb;
        lo[i] = f2bf(hv - b2f(hb));
    }
}
__global__ void concat_bf(const short* __restrict__ hgb, const short* __restrict__ htb,
                          short* __restrict__ cat) {
    for (int i = blockIdx.x * 256 + threadIdx.x; i < ROWS * 256; i += gridDim.x * 256) {
        int row = i >> 8, c4 = (i & 255) * 4;
        short4 v = (c4 < 512) ? *(const short4*)(hgb + ((size_t)row << 9) + c4)
                              : *(const short4*)(htb + ((size_t)row << 9) + c4 - 512);
        *(short4*)(cat + ((size_t)row << 10) + c4) = v;
    }
}
__global__ __launch_bounds__(256) void rowsq_k(const float* __restrict__ h, float* __restrict__ sq) {
    int row = blockIdx.x, tid = threadIdx.x;
    __shared__ float red[256];
    size_t base = (size_t)row << 9;
    float a = h[base + tid], b2 = h[base + tid + 256];
    float s = blockReduceSum(a * a + b2 * b2, red);
    if (tid == 0) sq[row] = s;
}

// ---------- pooling / classifier ----------
__global__ __launch_bounds__(256) void rowdot_k(const float* __restrict__ t, const float* __restrict__ w2,
                                                const float* __restrict__ b2, float* __restrict__ srow) {
    int row = blockIdx.x, tid = threadIdx.x;
    __shared__ float red[256];
    float s = blockReduceSum(t[(size_t)row * 256 + tid] * w2[tid], red);
    if (tid == 0) srow[row] = s + b2[0];
}
__global__ __launch_bounds__(256) void softmax_n_k(const float* __restrict__ srow, float* __restrict__ a,
                                                   float* __restrict__ out) {
    int b = blockIdx.x, tid = threadIdx.x;
    __shared__ float red[256];
    float mx = -INFINITY;
    for (int n = tid; n < NSEQ; n += 256) mx = fmaxf(mx, srow[b * NSEQ + n]);
    red[tid] = mx; __syncthreads();
    for (int s = 128; s > 0; s >>= 1) {
        if (tid < s) red[tid] = fmaxf(red[tid], red[tid + s]);
        __syncthreads();
    }
    mx = red[0]; __syncthreads();
    float sm = 0.f;
    for (int n = tid; n < NSEQ; n += 256) {
        float e = expf(srow[b * NSEQ + n] - mx);
        a[b * NSEQ + n] = e; sm += e;
    }
    float inv = 1.f / blockReduceSum(sm, red);
    for (int n = tid; n < NSEQ; n += 256) {
        float v = a[b * NSEQ + n] * inv;
        a[b * NSEQ + n] = v;
        out[2 + b * NSEQ + n] = v;
    }
}
__global__ __launch_bounds__(256) void pool_part(const float* __restrict__ hf, const float* __restrict__ a,
                                                 float* __restrict__ part) {
    int b = blockIdx.y, chunk = blockIdx.x, tid = threadIdx.x;
    float a0 = 0.f, a1 = 0.f;
    for (int r = 0; r < 64; ++r) {
        int n = chunk * 64 + r;
        float wgt = a[b * NSEQ + n];
        const float* row = hf + ((size_t)(b * NSEQ + n) << 9);
        a0 = fmaf(row[tid], wgt, a0);
        a1 = fmaf(row[tid + 256], wgt, a1);
    }
    part[((b * 32 + chunk) << 9) + tid] = a0;
    part[((b * 32 + chunk) << 9) + tid + 256] = a1;
}
__global__ __launch_bounds__(256) void pool_fin(const float* __restrict__ part, float* __restrict__ Mb,
                                                float* __restrict__ out) {
    int b = blockIdx.x, tid = threadIdx.x;
    float s0 = 0.f, s1 = 0.f;
    for (int ch = 0; ch < 32; ++ch) {
        s0 += part[((b * 32 + ch) << 9) + tid];
        s1 += part[((b * 32 + ch) << 9) + tid + 256];
    }
    Mb[b * 512 + tid] = s0; Mb[b * 512 + tid + 256] = s1;
    out[2 + ROWS + b * 512 + tid] = s0; out[2 + ROWS + b * 512 + tid + 256] = s1;
}
__global__ __launch_bounds__(256) void classifier_k(const float* __restrict__ Mb,
        const float* __restrict__ w1, const float* __restrict__ b1,
        const float* __restrict__ w2, const float* __restrict__ b2, float* __restrict__ out) {
    int b = blockIdx.x, tid = threadIdx.x;
    __shared__ float Ms[512];
    __shared__ float red[256];
    for (int c = tid; c < 512; c += 256) Ms[c] = Mb[b * 512 + c];
    __syncthreads();
    float acc = 0.f;
    for (int c = 0; c < 512; ++c) acc = fmaf(Ms[c], w1[tid * 512 + c], acc);
    acc += b1[tid];
    float hj = acc > 0.f ? acc : expm1f(acc);   // ELU alpha=1
    float s = blockReduceSum(hj * w2[tid], red);
    if (tid == 0) out[b] = s + b2[0];
}

extern "C" void kernel_launch(void* const* d_in, const int* in_sizes, int n_in,
                              void* d_out, int out_size, void* d_ws, size_t ws_size,
                              hipStream_t stream)
{
    const float* X      = (const float*)d_in[0];
    const float* Wstart = (const float*)d_in[1];
    const float* Bstart = (const float*)d_in[2];
    const float* GluW   = (const float*)d_in[3];
    const float* GluB   = (const float*)d_in[4];
    const float* GcnW   = (const float*)d_in[5];
    const float* GcnB   = (const float*)d_in[6];
    const float* GcnG   = (const float*)d_in[7];
    const float* GcnBe  = (const float*)d_in[8];
    const float* QkvW   = (const float*)d_in[9];
    const float* QkvB   = (const float*)d_in[10];
    const float* OutW   = (const float*)d_in[11];
    const float* OutB   = (const float*)d_in[12];
    const float* Ln1G   = (const float*)d_in[13];
    const float* Ln1B   = (const float*)d_in[14];
    const float* Ffn1W  = (const float*)d_in[15];
    const float* Ffn1B  = (const float*)d_in[16];
    const float* Ffn2W  = (const float*)d_in[17];
    const float* Ffn2B  = (const float*)d_in[18];
    const float* Ln2G   = (const float*)d_in[19];
    const float* Ln2B   = (const float*)d_in[20];
    const float* FusW   = (const float*)d_in[21];
    const float* FusB   = (const float*)d_in[22];
    const float* AW1    = (const float*)d_in[23];
    const float* AB1    = (const float*)d_in[24];
    const float* AW2    = (const float*)d_in[25];
    const float* AB2    = (const float*)d_in[26];
    const float* CW1    = (const float*)d_in[27];
    const float* CB1    = (const float*)d_in[28];
    const float* CW2    = (const float*)d_in[29];
    const float* CB2    = (const float*)d_in[30];
    float* out = (float*)d_out;

    if (ws_size < 86 * MB) return;

    char* w = (char*)d_ws;
    // bf16 weight arena [0,13MB)
    short* Wb = (short*)w;
    short* wbStart = Wb;
    short* wbGlu   = Wb + 524288;
    short* wbGcn   = Wb + 1048576;
    short* wbQkv   = Wb + 1572864;
    short* wbOut   = Wb + 3145728;
    short* wbFfn1  = Wb + 3670016;
    short* wbFfn2  = Wb + 4718592;
    short* wbFus   = Wb + 5767168;
    short* wbAw1   = Wb + 6291456;
    // small [13MB,14MB)
    float* sq   = (float*)(w + 13 * MB);
    int*   idx  = (int*)  (w + 13 * MB + (16u << 10));
    float* srow = (float*)(w + 13 * MB + (176u << 10));
    float* afb  = (float*)(w + 13 * MB + (192u << 10));
    float* Mbuf = (float*)(w + 13 * MB + (208u << 10));
    float* part = (float*)(w + 13 * MB + (212u << 10));
    float* Ml   = (float*)(w + 13 * MB + (384u << 10));   // 512KB
    // overlapped big buffers
    short* Xbf  = (short*)(w + 14 * MB);   // 8MB -> hg after fc_start
    float* hg   = (float*)(w + 14 * MB);
    short* hpreb= (short*)(w + 22 * MB);   // 4MB -> hgb after GLU gemm
    short* hgb  = (short*)(w + 22 * MB);
    float* big  = (float*)(w + 26 * MB);   // 26..42MB: vg/D2/gcn-s/Op/out-proj
    float* ffn2o= (float*)(w + 42 * MB);   // 8MB
    float* h    = (float*)(w + 50 * MB);   // 8MB; doubles as ht residual
    short* hhi  = (short*)(w + 58 * MB);   // 4MB; -> hf low half after loop
    short* hlo  = (short*)(w + 62 * MB);   // 4MB; dead after gram -> htb
    short* htb  = (short*)(w + 62 * MB);   // 4MB (transformer bf16 state)
    float* hf   = (float*)(w + 58 * MB);   // 8MB (after transformer loop)
    short* Vt   = (short*)(w + 66 * MB);   // 4MB; -> hfb after loop
    short* hfb  = (short*)(w + 66 * MB);
    short* aob  = (short*)(w + 70 * MB);   // 4MB; -> t256 (pool)
    float* t256 = (float*)(w + 70 * MB);
    short* Qb   = (short*)(w + 74 * MB);   // 4MB  (OUTMODE=3: K=Qb+4MB, V=Qb+8MB)
    short* Kb   = (short*)(w + 78 * MB);   // 4MB
    short* Vtmp = (short*)(w + 82 * MB);   // 4MB
    short* ffb  = (short*)(w + 74 * MB);   // 8MB (ffn1 out; Qb/Kb dead) -> catb
    short* catb = (short*)(w + 74 * MB);

    dim3 blk(256);

    // convert X + all GEMM weights to bf16
    CvtArgs ca;
    ca.src[0] = X;     ca.dst[0] = Xbf;     ca.n4[0] = ROWS * 1024 / 4;
    ca.src[1] = Wstart;ca.dst[1] = wbStart; ca.n4[1] = 524288 / 4;
    ca.src[2] = GluW;  ca.dst[2] = wbGlu;   ca.n4[2] = 524288 / 4;
    ca.src[3] = GcnW;  ca.dst[3] = wbGcn;   ca.n4[3] = 524288 / 4;
    ca.src[4] = QkvW;  ca.dst[4] = wbQkv;   ca.n4[4] = 1572864 / 4;
    ca.src[5] = OutW;  ca.dst[5] = wbOut;   ca.n4[5] = 524288 / 4;
    ca.src[6] = Ffn1W; ca.dst[6] = wbFfn1;  ca.n4[6] = 1048576 / 4;
    ca.src[7] = Ffn2W; ca.dst[7] = wbFfn2;  ca.n4[7] = 1048576 / 4;
    ca.src[8] = FusW;  ca.dst[8] = wbFus;   ca.n4[8] = 524288 / 4;
    ca.src[9] = AW1;   ca.dst[9] = wbAw1;   ca.n4[9] = 131072 / 4;
    cvt_k<<<dim3(256, 10), blk, 0, stream>>>(ca);

    // fc_start -> GLU
    mfma_gemm<64, 1><<<dim3(4, 64), 128, 0, stream>>>(Xbf, wbStart, Bstart, nullptr, hpreb, ROWS, 512, 1024);
    mfma_gemm<128, 0><<<dim3(8, 32), 256, 0, stream>>>(hpreb, wbGlu, GluB, big, nullptr, ROWS, 1024, 512);
    glu_k<<<dim3(2048), blk, 0, stream>>>(big, h, hg, hhi, hlo);
    rowsq_k<<<dim3(ROWS), blk, 0, stream>>>(h, sq);

    // KNN graph (hi/lo split gram, f32-equivalent ranking)
    for (int b = 0; b < 2; ++b) {
        mfma_gram<<<dim3(16, 16), blk, 0, stream>>>(hhi + (size_t)b * NSEQ * 512,
                                                    hlo + (size_t)b * NSEQ * 512,
                                                    sq + b * NSEQ, big);
        topk9_k<<<dim3(NSEQ), blk, 0, stream>>>(big, idx + b * NSEQ * KNN);
    }

    // GCN branch
    const short* gA = hhi;
    for (int i = 0; i < 2; ++i) {
        mfma_gemm<64, 0><<<dim3(4, 64), 128, 0, stream>>>(gA, wbGcn + (size_t)i * 262144,
                                                          GcnB + i * 512, big, nullptr, ROWS, 512, 512);
        gcn_post<<<dim3(ROWS), blk, 0, stream>>>(big, idx, GcnG + i * 512, GcnBe + i * 512, hg, hgb);
        gA = hgb;
    }

    // Transformer branch (h doubles as ht residual)
    const short* tA = hhi;
    for (int i = 0; i < 2; ++i) {
        mfma_gemm<64, 3><<<dim3(12, 64), 128, 0, stream>>>(tA, wbQkv + (size_t)i * 786432,
                                                           QkvB + i * 1536, nullptr, Qb, ROWS, 1536, 512);
        vtr_k<<<dim3(32, 16), blk, 0, stream>>>(Vtmp, Vt);
        flash_attn<<<dim3(32, 2, 16), blk, 0, stream>>>(Qb, Kb, Vt, big, Ml);
        merge_k<<<dim3(8192), blk, 0, stream>>>(big, Ml, aob);
        mfma_gemm<64, 0><<<dim3(4, 64), 128, 0, stream>>>(aob, wbOut + (size_t)i * 262144,
                                                          OutB + i * 512, big, nullptr, ROWS, 512, 512);
        ln_res<<<dim3(ROWS), blk, 0, stream>>>(h, big, Ln1G + i * 512, Ln1B + i * 512, htb);
        mfma_gemm<128, 4><<<dim3(8, 32), 256, 0, stream>>>(htb, wbFfn1 + (size_t)i * 524288,
                                                           Ffn1B + i * 1024, nullptr, ffb, ROWS, 1024, 512);
        mfma_gemm<64, 0><<<dim3(4, 64), 128, 0, stream>>>(ffb, wbFfn2 + (size_t)i * 524288,
                                                          Ffn2B + i * 512, ffn2o, nullptr, ROWS, 512, 1024);
        ln_res<<<dim3(ROWS), blk, 0, stream>>>(h, ffn2o, Ln2G + i * 512, Ln2B + i * 512, htb);
        tA = htb;
    }

    // fusion
    concat_bf<<<dim3(2048), blk, 0, stream>>>(hgb, htb, catb);
    mfma_gemm<64, 2><<<dim3(4, 64), 128, 0, stream>>>(catb, wbFus, FusB, hf, hfb, ROWS, 512, 1024);

    // gated attention pooling (tanh fused into GEMM)
    mfma_gemm<64, 5><<<dim3(2, 64), 128, 0, stream>>>(hfb, wbAw1, AB1, t256, nullptr, ROWS, 256, 512);
    rowdot_k<<<dim3(ROWS), blk, 0, stream>>>(t256, AW2, AB2, srow);
    softmax_n_k<<<dim3(2), blk, 0, stream>>>(srow, afb, out);
    pool_part<<<dim3(32, 2), blk, 0, stream>>>(hf, afb, part);
    pool_fin<<<dim3(2), blk, 0, stream>>>(part, Mbuf, out);

    // classifier
    classifier_k<<<dim3(2), blk, 0, stream>>>(Mbuf, CW1, CB1, CW2, CB2, out);
}

// Round 7
// 511.205 us; speedup vs baseline: 13.5677x; 1.3356x over previous
//
#include <hip/hip_runtime.h>
#include <hip/hip_bf16.h>
#include <math.h>

#define NSEQ 2048
#define ROWS 4096   // B*N
#define KNN 9
#define MB (1ull << 20)

typedef short bh8 __attribute__((ext_vector_type(8)));   // 8 bf16 in 4 VGPRs
typedef float f4v __attribute__((ext_vector_type(4)));
typedef unsigned long long u64k;

__device__ __forceinline__ short f2bf(float f) {
    union { float f; unsigned u; } v; v.f = f;
    unsigned r = (v.u + 0x7fffu + ((v.u >> 16) & 1u)) >> 16;
    return (short)r;
}
__device__ __forceinline__ float b2f(short s) {
    union { unsigned u; float f; } v; v.u = ((unsigned)(unsigned short)s) << 16; return v.f;
}

// async global->LDS, 16B per lane; LDS dest is wave-uniform base + lane*16
__device__ __forceinline__ void gload16(const void* g, void* l) {
    __builtin_amdgcn_global_load_lds(
        (const __attribute__((address_space(1))) void*)g,
        (__attribute__((address_space(3))) void*)l, 16, 0, 0);
}

// ---------- block reduce (blockDim.x == 256) ----------
__device__ __forceinline__ float blockReduceSum(float v, float* red) {
    int tid = threadIdx.x;
    red[tid] = v; __syncthreads();
    for (int s = 128; s > 0; s >>= 1) {
        if (tid < s) red[tid] += red[tid + s];
        __syncthreads();
    }
    float r = red[0]; __syncthreads();
    return r;
}

// ---------- f32 -> bf16 conversion (weights + X), 10 segments ----------
struct CvtArgs { const float* src[10]; short* dst[10]; int n4[10]; };
__global__ __launch_bounds__(256) void cvt_k(CvtArgs a) {
    int s = blockIdx.y;
    const float* sp = a.src[s]; short* dp = a.dst[s]; int n = a.n4[s];
    for (int i = blockIdx.x * 256 + threadIdx.x; i < n; i += gridDim.x * 256) {
        float4 v = ((const float4*)sp)[i];
        short4 o; o.x = f2bf(v.x); o.y = f2bf(v.y); o.z = f2bf(v.z); o.w = f2bf(v.w);
        ((short4*)dp)[i] = o;
    }
}

// ---------- MFMA GEMM: C[M,N] = A[M,K](bf16) @ W[N,K](bf16)^T + bias ----------
// 64x64 tile, BK=64, 4 waves (2x2), wave tile 32x32 (2x2 frags of 16x16).
// OUTMODE: 0=f32, 1=bf16, 2=both, 3=qkv special (Q*0.125*log2e/K/V head-major bf16;
//          K at Cb+4MB, V at Cb+8MB), 4=gelu->bf16, 5=tanh->f32
template <int OUTMODE>
__global__ __launch_bounds__(256) void mfma_gemm(
        const short* __restrict__ A, const short* __restrict__ W,
        const float* __restrict__ bias, float* __restrict__ Cf, short* __restrict__ Cb,
        int M, int N, int K)
{
    __shared__ short As[64 * 64];
    __shared__ short Bs[64 * 64];
    int tid = threadIdx.x;
    int wv = tid >> 6, l = tid & 63;
    int g = l >> 4, c = l & 15;
    int wr = wv >> 1, wc = wv & 1;
    int bm = blockIdx.y * 64, bn = blockIdx.x * 64;
    int sr = l >> 3, sc = (l & 7) * 8;
    const short* Ap = A + (size_t)(bm + wv * 16 + sr) * K + sc;
    const short* Wp = W + (size_t)(bn + wv * 16 + sr) * K + sc;
    short* AsB = As + (wv * 16) * 64;
    short* BsB = Bs + (wv * 16) * 64;
    f4v acc[2][2] = {};
    for (int k0 = 0; k0 < K; k0 += 64) {
        __syncthreads();
        gload16(Ap + k0, AsB);
        gload16(Ap + (size_t)8 * K + k0, AsB + 8 * 64);
        gload16(Wp + k0, BsB);
        gload16(Wp + (size_t)8 * K + k0, BsB + 8 * 64);
        __syncthreads();
        #pragma unroll
        for (int ks = 0; ks < 2; ++ks) {
            bh8 af[2], bf_[2];
            #pragma unroll
            for (int mi = 0; mi < 2; ++mi)
                af[mi] = *(const bh8*)(As + (wr * 32 + mi * 16 + c) * 64 + ks * 32 + g * 8);
            #pragma unroll
            for (int ni = 0; ni < 2; ++ni)
                bf_[ni] = *(const bh8*)(Bs + (wc * 32 + ni * 16 + c) * 64 + ks * 32 + g * 8);
            #pragma unroll
            for (int mi = 0; mi < 2; ++mi)
                #pragma unroll
                for (int ni = 0; ni < 2; ++ni)
                    acc[mi][ni] = __builtin_amdgcn_mfma_f32_16x16x32_bf16(af[mi], bf_[ni], acc[mi][ni], 0, 0, 0);
        }
    }
    short* Kb_  = (OUTMODE == 3) ? Cb + 2097152 : nullptr;   // +4MB
    short* Vt_  = (OUTMODE == 3) ? Cb + 4194304 : nullptr;   // +8MB
    #pragma unroll
    for (int mi = 0; mi < 2; ++mi) {
        int row = bm + wr * 32 + mi * 16 + g * 4;
        #pragma unroll
        for (int ni = 0; ni < 2; ++ni) {
            int col = bn + wc * 32 + ni * 16 + c;
            float bv = bias[col];
            #pragma unroll
            for (int rr = 0; rr < 4; ++rr) {
                float v = acc[mi][ni][rr] + bv;
                if (OUTMODE == 0) Cf[(size_t)(row + rr) * N + col] = v;
                else if (OUTMODE == 1) Cb[(size_t)(row + rr) * N + col] = f2bf(v);
                else if (OUTMODE == 2) {
                    Cf[(size_t)(row + rr) * N + col] = v;
                    Cb[(size_t)(row + rr) * N + col] = f2bf(v);
                } else if (OUTMODE == 3) {
                    int b = (row + rr) >> 11, n = (row + rr) & 2047;
                    if (col < 512) {
                        int h = col >> 6, d = col & 63;
                        Cb[(((size_t)(b * 8 + h) * NSEQ + n) << 6) + d] = f2bf(v * 0.18033688f);
                    } else if (col < 1024) {
                        int cc = col - 512, h = cc >> 6, d = cc & 63;
                        Kb_[(((size_t)(b * 8 + h) * NSEQ + n) << 6) + d] = f2bf(v);
                    } else {
                        int cc = col - 1024, h = cc >> 6, d = cc & 63;
                        Vt_[(((size_t)(b * 8 + h) * NSEQ + n) << 6) + d] = f2bf(v);
                    }
                } else if (OUTMODE == 4) {
                    Cb[(size_t)(row + rr) * N + col] = f2bf(0.5f * v * (1.f + erff(v * 0.70710678118654752f)));
                } else if (OUTMODE == 5) {
                    Cf[(size_t)(row + rr) * N + col] = tanhf(v);
                }
            }
        }
    }
}

// ---------- gram for KNN distances, hi/lo split, 64x64 tiles ----------
__global__ __launch_bounds__(256) void mfma_gram(
        const short* __restrict__ Hi, const short* __restrict__ Lo,
        const float* __restrict__ SQ, float* __restrict__ D2)
{
    __shared__ short HiR[64 * 64], LoR[64 * 64], HiC[64 * 64], LoC[64 * 64];
    int tid = threadIdx.x;
    int wv = tid >> 6, l = tid & 63;
    int g = l >> 4, c = l & 15;
    int wr = wv >> 1, wc = wv & 1;
    int bm = blockIdx.y * 64, bn = blockIdx.x * 64;
    int sr = l >> 3, sc = (l & 7) * 8;
    const short* hiR = Hi + (size_t)(bm + wv * 16 + sr) * 512 + sc;
    const short* loR = Lo + (size_t)(bm + wv * 16 + sr) * 512 + sc;
    const short* hiC = Hi + (size_t)(bn + wv * 16 + sr) * 512 + sc;
    const short* loC = Lo + (size_t)(bn + wv * 16 + sr) * 512 + sc;
    int ldsOff = (wv * 16) * 64;
    f4v acc[2][2] = {};
    for (int k0 = 0; k0 < 512; k0 += 64) {
        __syncthreads();
        gload16(hiR + k0, HiR + ldsOff);
        gload16(hiR + (size_t)8 * 512 + k0, HiR + ldsOff + 8 * 64);
        gload16(loR + k0, LoR + ldsOff);
        gload16(loR + (size_t)8 * 512 + k0, LoR + ldsOff + 8 * 64);
        gload16(hiC + k0, HiC + ldsOff);
        gload16(hiC + (size_t)8 * 512 + k0, HiC + ldsOff + 8 * 64);
        gload16(loC + k0, LoC + ldsOff);
        gload16(loC + (size_t)8 * 512 + k0, LoC + ldsOff + 8 * 64);
        __syncthreads();
        #pragma unroll
        for (int ks = 0; ks < 2; ++ks) {
            bh8 hr[2], lr_[2], hc[2], lc[2];
            #pragma unroll
            for (int mi = 0; mi < 2; ++mi) {
                int o = (wr * 32 + mi * 16 + c) * 64 + ks * 32 + g * 8;
                hr[mi] = *(const bh8*)(HiR + o);
                lr_[mi] = *(const bh8*)(LoR + o);
            }
            #pragma unroll
            for (int ni = 0; ni < 2; ++ni) {
                int o = (wc * 32 + ni * 16 + c) * 64 + ks * 32 + g * 8;
                hc[ni] = *(const bh8*)(HiC + o);
                lc[ni] = *(const bh8*)(LoC + o);
            }
            #pragma unroll
            for (int mi = 0; mi < 2; ++mi)
                #pragma unroll
                for (int ni = 0; ni < 2; ++ni) {
                    acc[mi][ni] = __builtin_amdgcn_mfma_f32_16x16x32_bf16(hr[mi], hc[ni], acc[mi][ni], 0, 0, 0);
                    acc[mi][ni] = __builtin_amdgcn_mfma_f32_16x16x32_bf16(hr[mi], lc[ni], acc[mi][ni], 0, 0, 0);
                    acc[mi][ni] = __builtin_amdgcn_mfma_f32_16x16x32_bf16(lr_[mi], hc[ni], acc[mi][ni], 0, 0, 0);
                }
        }
    }
    #pragma unroll
    for (int mi = 0; mi < 2; ++mi) {
        int row = bm + wr * 32 + mi * 16 + g * 4;
        #pragma unroll
        for (int ni = 0; ni < 2; ++ni) {
            int col = bn + wc * 32 + ni * 16 + c;
            float sqc = SQ[col];
            #pragma unroll
            for (int rr = 0; rr < 4; ++rr)
                D2[(size_t)(row + rr) * NSEQ + col] = SQ[row + rr] + sqc - 2.f * acc[mi][ni][rr];
        }
    }
}

// ---------- top-9 smallest per row: u64 keys, sort8 + LDS merge tree ----------
__global__ __launch_bounds__(256) void topk9_k(const float* __restrict__ D2, int* __restrict__ idx)
{
    int n = blockIdx.x, tid = threadIdx.x;
    __shared__ u64k lists[256][9];
    u64k a[8];
    union { float f; unsigned u; } cv;
    #pragma unroll
    for (int j = 0; j < 8; ++j) {
        int mcol = tid + j * 256;
        cv.f = fmaxf(D2[(size_t)n * NSEQ + mcol], 0.f);
        a[j] = ((u64k)cv.u << 32) | (unsigned)mcol;
    }
    // Batcher odd-even sort-8 (19 CEs, static indices)
    #define CE(i,j) { u64k x = a[i], y = a[j]; bool t = x < y; a[i] = t ? x : y; a[j] = t ? y : x; }
    CE(0,1) CE(2,3) CE(4,5) CE(6,7)
    CE(0,2) CE(1,3) CE(4,6) CE(5,7)
    CE(1,2) CE(5,6)
    CE(0,4) CE(1,5) CE(2,6) CE(3,7)
    CE(2,4) CE(3,5)
    CE(1,2) CE(3,4) CE(5,6)
    #undef CE
    #pragma unroll
    for (int j = 0; j < 8; ++j) lists[tid][j] = a[j];
    lists[tid][8] = ~0ull;
    __syncthreads();
    for (int s = 128; s >= 1; s >>= 1) {
        if (tid < s) {
            u64k out[9];
            u64k* Al = lists[tid];
            u64k* Bl = lists[tid + s];
            int ia = 0, ib = 0;
            #pragma unroll
            for (int o = 0; o < 9; ++o) {
                u64k av = Al[ia], bv = Bl[ib];
                bool t = av <= bv;
                out[o] = t ? av : bv;
                ia += t; ib += !t;
            }
            #pragma unroll
            for (int o = 0; o < 9; ++o) Al[o] = out[o];
        }
        __syncthreads();
    }
    if (tid < 9) idx[n * KNN + tid] = (int)(lists[0][tid] & 0xffffffffu);
}

// ---------- GCN aggregate + LN + leaky + residual (writes f32 + bf16) ----------
__global__ __launch_bounds__(256) void gcn_post(
        const float* __restrict__ s, const int* __restrict__ idx,
        const float* __restrict__ g, const float* __restrict__ be,
        float* __restrict__ hg, short* __restrict__ hgb)
{
    int row = blockIdx.x, tid = threadIdx.x;
    int bb = row >> 11;
    __shared__ float os[512];
    __shared__ float red[256];
    int id[KNN];
    #pragma unroll
    for (int j = 0; j < KNN; ++j) id[j] = idx[row * KNN + j] + (bb << 11);
    for (int c = tid; c < 512; c += 256) {
        float acc = 0.f;
        #pragma unroll
        for (int j = 0; j < KNN; ++j) acc += s[((size_t)id[j] << 9) + c];
        os[c] = acc * (1.f / 9.f);
    }
    __syncthreads();
    float mean = blockReduceSum(os[tid] + os[tid + 256], red) * (1.f / 512.f);
    float d0 = os[tid] - mean, d1 = os[tid + 256] - mean;
    float var = blockReduceSum(d0 * d0 + d1 * d1, red) * (1.f / 512.f);
    float rs = rsqrtf(var + 1e-5f);
    size_t base = (size_t)row << 9;
    for (int c = tid; c < 512; c += 256) {
        float y = (os[c] - mean) * rs * g[c] + be[c];
        y = y > 0.f ? y : 0.2f * y;
        float nv = y + hg[base + c];
        hg[base + c] = nv;
        hgb[base + c] = f2bf(nv);
    }
}

// ---------- x = LN(x + r)*g + b (writes f32 + bf16) ----------
__global__ __launch_bounds__(256) void ln_res(
        float* __restrict__ x, const float* __restrict__ r,
        const float* __restrict__ g, const float* __restrict__ b, short* __restrict__ xb)
{
    int row = blockIdx.x, tid = threadIdx.x;
    __shared__ float xs[512];
    __shared__ float red[256];
    size_t base = (size_t)row << 9;
    for (int c = tid; c < 512; c += 256) xs[c] = x[base + c] + r[base + c];
    __syncthreads();
    float mean = blockReduceSum(xs[tid] + xs[tid + 256], red) * (1.f / 512.f);
    float d0 = xs[tid] - mean, d1 = xs[tid + 256] - mean;
    float var = blockReduceSum(d0 * d0 + d1 * d1, red) * (1.f / 512.f);
    float rs = rsqrtf(var + 1e-5f);
    for (int c = tid; c < 512; c += 256) {
        float y = (xs[c] - mean) * rs * g[c] + b[c];
        x[base + c] = y;
        xb[base + c] = f2bf(y);
    }
}

// ---------- V [bh][n][64] -> Vt [bh][64][2048] (bf16 transpose) ----------
__global__ __launch_bounds__(256) void vtr_k(const short* __restrict__ Vtmp, short* __restrict__ Vt)
{
    int nt = blockIdx.x, bh = blockIdx.y;
    int t = threadIdx.x;
    #pragma unroll
    for (int it = 0; it < 2; ++it) {
        int idx = it * 256 + t;
        int d = idx >> 3, nc = (idx & 7) * 8;
        short tmp[8];
        #pragma unroll
        for (int j = 0; j < 8; ++j)
            tmp[j] = Vtmp[(((size_t)bh * NSEQ + nt * 64 + nc + j) << 6) + d];
        *(bh8*)(Vt + (((size_t)bh * 64 + d) << 11) + nt * 64 + nc) = *(const bh8*)tmp;
    }
}

// ---------- flash attention: LDS K/V, KV-split=2, log2-domain softmax ----------
// Q pre-scaled by 0.125*log2(e) so scores are log2-domain; exp2 via v_exp.
__global__ __launch_bounds__(256) void flash_attn(
        const short* __restrict__ Qb, const short* __restrict__ Kb,
        const short* __restrict__ Vt, float* __restrict__ Op, float* __restrict__ Ml)
{
    __shared__ short Ks[2][4096];
    __shared__ short Vs[2][4096];
    __shared__ char Pl[4][2048];
    int tid = threadIdx.x;
    int wid = tid >> 6, lane = tid & 63;
    int g = lane >> 4, c = lane & 15;
    int s = blockIdx.y, bh = blockIdx.z;
    int q0 = blockIdx.x * 64 + wid * 16;
    char* myP = Pl[wid];
    int srow = lane >> 3;                  // 0..7
    int sc8 = ((lane & 7) ^ srow) * 8;     // pre-swizzled source chunk (involution)
    int w8 = wid * 8;

    const short* KbB = Kb + ((size_t)bh * NSEQ + s * (NSEQ / 2)) * 64;
    const short* VtB = Vt + (size_t)bh * 64 * NSEQ + s * (NSEQ / 2);

    const short* qbase = Qb + ((size_t)bh * NSEQ + q0 + c) * 64 + g * 8;
    bh8 qa0 = *(const bh8*)(qbase);
    bh8 qa1 = *(const bh8*)(qbase + 32);

    bh8 ones;
    #pragma unroll
    for (int j = 0; j < 8; ++j) ones[j] = (short)0x3F80;   // bf16 1.0

    f4v o0 = {0,0,0,0}, o1 = {0,0,0,0}, o2 = {0,0,0,0}, o3 = {0,0,0,0};
    f4v ol = {0,0,0,0};                                     // row-sum (l) accumulator
    float m[4] = {-INFINITY,-INFINITY,-INFINITY,-INFINITY};

    #define FSTAGE(buf, kt) { \
        const short* kp_ = KbB + (size_t)(kt) * 64 * 64; \
        gload16(kp_ + (size_t)(w8 + srow) * 64 + sc8,        &Ks[buf][w8 * 64]); \
        gload16(kp_ + (size_t)(32 + w8 + srow) * 64 + sc8,   &Ks[buf][(32 + w8) * 64]); \
        const short* vp_ = VtB + (size_t)(kt) * 64; \
        gload16(vp_ + (size_t)(w8 + srow) * NSEQ + sc8,      &Vs[buf][w8 * 64]); \
        gload16(vp_ + (size_t)(32 + w8 + srow) * NSEQ + sc8, &Vs[buf][(32 + w8) * 64]); }

    FSTAGE(0, 0);
    __syncthreads();
    for (int t = 0; t < 16; ++t) {
        int cur = t & 1;
        if (t < 15) FSTAGE(cur ^ 1, t + 1);
        // ---- QK^T (log2 domain) from swizzled LDS ----
        f4v sv[4];
        #pragma unroll
        for (int cb = 0; cb < 4; ++cb) {
            int row = cb * 16 + c;
            const short* kr = &Ks[cur][row * 64];
            bh8 kb0 = *(const bh8*)(kr + ((g ^ (row & 7)) * 8));
            bh8 kb1 = *(const bh8*)(kr + (((4 + g) ^ (row & 7)) * 8));
            f4v a = {0,0,0,0};
            a = __builtin_amdgcn_mfma_f32_16x16x32_bf16(qa0, kb0, a, 0, 0, 0);
            a = __builtin_amdgcn_mfma_f32_16x16x32_bf16(qa1, kb1, a, 0, 0, 0);
            sv[cb] = a;
        }
        // ---- tile max per row (16-lane col group) ----
        float mt[4];
        #pragma unroll
        for (int r = 0; r < 4; ++r) {
            float v = fmaxf(fmaxf(sv[0][r], sv[1][r]), fmaxf(sv[2][r], sv[3][r]));
            v = fmaxf(v, __shfl_xor(v, 1));
            v = fmaxf(v, __shfl_xor(v, 2));
            v = fmaxf(v, __shfl_xor(v, 4));
            v = fmaxf(v, __shfl_xor(v, 8));
            mt[r] = v;
        }
        // ---- defer-max: rescale only when max grows by > 6 (log2) ----
        bool need = (mt[0] > m[0] + 6.f) | (mt[1] > m[1] + 6.f) |
                    (mt[2] > m[2] + 6.f) | (mt[3] > m[3] + 6.f);
        if (__any(need)) {
            f4v alv;
            #pragma unroll
            for (int r = 0; r < 4; ++r) {
                float mn = fmaxf(m[r], mt[r]);
                alv[r] = __builtin_amdgcn_exp2f(m[r] - mn);
                m[r] = mn;
            }
            o0 *= alv; o1 *= alv; o2 *= alv; o3 *= alv; ol *= alv;
        }
        // ---- P = 2^(S - m), bf16 via v_cvt_pk, swizzled LDS ----
        #pragma unroll
        for (int cb = 0; cb < 4; ++cb) {
            #pragma unroll
            for (int r = 0; r < 4; ++r) {
                float p = __builtin_amdgcn_exp2f(sv[cb][r] - m[r]);
                unsigned pk;
                asm("v_cvt_pk_bf16_f32 %0, %1, %2" : "=v"(pk) : "v"(p), "v"(p));
                int row = g * 4 + r;
                int byte = row * 128 + (((cb * 16 + c) * 2) ^ ((row & 7) << 4));
                *(short*)(myP + byte) = (short)pk;
            }
        }
        // ---- PV + l via ones-column MFMA ----
        bh8 pa0 = *(const bh8*)(myP + c * 128 + (( 0 + g * 16) ^ ((c & 7) << 4)));
        bh8 pa1 = *(const bh8*)(myP + c * 128 + ((64 + g * 16) ^ ((c & 7) << 4)));
        ol = __builtin_amdgcn_mfma_f32_16x16x32_bf16(pa0, ones, ol, 0, 0, 0);
        ol = __builtin_amdgcn_mfma_f32_16x16x32_bf16(pa1, ones, ol, 0, 0, 0);
        #pragma unroll
        for (int db = 0; db < 4; ++db) {
            int row = db * 16 + c;
            const short* vr = &Vs[cur][row * 64];
            bh8 vb0 = *(const bh8*)(vr + ((g ^ (row & 7)) * 8));
            bh8 vb1 = *(const bh8*)(vr + (((4 + g) ^ (row & 7)) * 8));
            f4v* op = (db == 0) ? &o0 : (db == 1) ? &o1 : (db == 2) ? &o2 : &o3;
            *op = __builtin_amdgcn_mfma_f32_16x16x32_bf16(pa0, vb0, *op, 0, 0, 0);
            *op = __builtin_amdgcn_mfma_f32_16x16x32_bf16(pa1, vb1, *op, 0, 0, 0);
        }
        __syncthreads();
    }
    #undef FSTAGE
    #pragma unroll
    for (int r = 0; r < 4; ++r) {
        size_t rb = (((size_t)(s * 16 + bh) * NSEQ) + q0 + g * 4 + r) * 64 + c;
        Op[rb]      = o0[r];
        Op[rb + 16] = o1[r];
        Op[rb + 32] = o2[r];
        Op[rb + 48] = o3[r];
    }
    if (c == 0) {
        #pragma unroll
        for (int r = 0; r < 4; ++r) {
            size_t mb = (((size_t)(s * 16 + bh) * NSEQ) + q0 + g * 4 + r) * 2;
            Ml[mb] = m[r]; Ml[mb + 1] = ol[r];
        }
    }
}

// ---------- merge 2 KV-splits -> bf16 attention output (log2-domain m) ----------
__global__ __launch_bounds__(256) void merge_k(const float* __restrict__ Op, const float* __restrict__ Ml,
                                               short* __restrict__ aob)
{
    int idx = blockIdx.x * 256 + threadIdx.x;   // 16*2048*64
    int d = idx & 63, q = (idx >> 6) & 2047, bh = idx >> 17;
    size_t r0 = (size_t)bh * NSEQ + q;
    size_t r1 = (size_t)(16 + bh) * NSEQ + q;
    float m0 = Ml[r0 * 2], l0 = Ml[r0 * 2 + 1];
    float m1 = Ml[r1 * 2], l1 = Ml[r1 * 2 + 1];
    float M = fmaxf(m0, m1);
    float w0 = __builtin_amdgcn_exp2f(m0 - M), w1 = __builtin_amdgcn_exp2f(m1 - M);
    float L = l0 * w0 + l1 * w1;
    float v = (Op[r0 * 64 + d] * w0 + Op[r1 * 64 + d] * w1) / L;
    int b = bh >> 3, h = bh & 7;
    aob[((size_t)(b * NSEQ + q)) * 512 + h * 64 + d] = f2bf(v);
}

// ---------- GLU per-row: h, copies, hi/lo split, fused row-sq ----------
__global__ __launch_bounds__(256) void glu_row_k(const float* __restrict__ vg, float* __restrict__ h,
        float* __restrict__ hgf, short* __restrict__ hi, short* __restrict__ lo,
        float* __restrict__ sq) {
    int row = blockIdx.x, tid = threadIdx.x;
    __shared__ float red[256];
    size_t vb = (size_t)row << 10;
    size_t hb = (size_t)row << 9;
    float ss = 0.f;
    #pragma unroll
    for (int j = 0; j < 2; ++j) {
        int c = tid + j * 256;
        float v = vg[vb + c], gt = vg[vb + 512 + c];
        float hv = v * (1.f / (1.f + __expf(-gt)));
        h[hb + c] = hv; hgf[hb + c] = hv;
        short hbb = f2bf(hv);
        hi[hb + c] = hbb;
        lo[hb + c] = f2bf(hv - b2f(hbb));
        ss = fmaf(hv, hv, ss);
    }
    float sm = blockReduceSum(ss, red);
    if (tid == 0) sq[row] = sm;
}

__global__ void concat_bf(const short* __restrict__ hgb, const short* __restrict__ htb,
                          short* __restrict__ cat) {
    for (int i = blockIdx.x * 256 + threadIdx.x; i < ROWS * 256; i += gridDim.x * 256) {
        int row = i >> 8, c4 = (i & 255) * 4;
        short4 v = (c4 < 512) ? *(const short4*)(hgb + ((size_t)row << 9) + c4)
                              : *(const short4*)(htb + ((size_t)row << 9) + c4 - 512);
        *(short4*)(cat + ((size_t)row << 10) + c4) = v;
    }
}

// ---------- pooling / classifier ----------
__global__ __launch_bounds__(256) void rowdot_k(const float* __restrict__ t, const float* __restrict__ w2,
                                                const float* __restrict__ b2, float* __restrict__ srow) {
    int row = blockIdx.x, tid = threadIdx.x;
    __shared__ float red[256];
    float s = blockReduceSum(t[(size_t)row * 256 + tid] * w2[tid], red);
    if (tid == 0) srow[row] = s + b2[0];
}
__global__ __launch_bounds__(256) void softmax_n_k(const float* __restrict__ srow, float* __restrict__ a,
                                                   float* __restrict__ out) {
    int b = blockIdx.x, tid = threadIdx.x;
    __shared__ float red[256];
    float mx = -INFINITY;
    for (int n = tid; n < NSEQ; n += 256) mx = fmaxf(mx, srow[b * NSEQ + n]);
    red[tid] = mx; __syncthreads();
    for (int s = 128; s > 0; s >>= 1) {
        if (tid < s) red[tid] = fmaxf(red[tid], red[tid + s]);
        __syncthreads();
    }
    mx = red[0]; __syncthreads();
    float sm = 0.f;
    for (int n = tid; n < NSEQ; n += 256) {
        float e = expf(srow[b * NSEQ + n] - mx);
        a[b * NSEQ + n] = e; sm += e;
    }
    float inv = 1.f / blockReduceSum(sm, red);
    for (int n = tid; n < NSEQ; n += 256) {
        float v = a[b * NSEQ + n] * inv;
        a[b * NSEQ + n] = v;
        out[2 + b * NSEQ + n] = v;
    }
}
__global__ __launch_bounds__(256) void pool_part(const float* __restrict__ hf, const float* __restrict__ a,
                                                 float* __restrict__ part) {
    int b = blockIdx.y, chunk = blockIdx.x, tid = threadIdx.x;
    float a0 = 0.f, a1 = 0.f;
    for (int r = 0; r < 64; ++r) {
        int n = chunk * 64 + r;
        float wgt = a[b * NSEQ + n];
        const float* row = hf + ((size_t)(b * NSEQ + n) << 9);
        a0 = fmaf(row[tid], wgt, a0);
        a1 = fmaf(row[tid + 256], wgt, a1);
    }
    part[((b * 32 + chunk) << 9) + tid] = a0;
    part[((b * 32 + chunk) << 9) + tid + 256] = a1;
}
__global__ __launch_bounds__(256) void pool_fin(const float* __restrict__ part, float* __restrict__ Mb,
                                                float* __restrict__ out) {
    int b = blockIdx.x, tid = threadIdx.x;
    float s0 = 0.f, s1 = 0.f;
    for (int ch = 0; ch < 32; ++ch) {
        s0 += part[((b * 32 + ch) << 9) + tid];
        s1 += part[((b * 32 + ch) << 9) + tid + 256];
    }
    Mb[b * 512 + tid] = s0; Mb[b * 512 + tid + 256] = s1;
    out[2 + ROWS + b * 512 + tid] = s0; out[2 + ROWS + b * 512 + tid + 256] = s1;
}
__global__ __launch_bounds__(256) void classifier_k(const float* __restrict__ Mb,
        const float* __restrict__ w1, const float* __restrict__ b1,
        const float* __restrict__ w2, const float* __restrict__ b2, float* __restrict__ out) {
    int b = blockIdx.x, tid = threadIdx.x;
    __shared__ float Ms[512];
    __shared__ float red[256];
    for (int c = tid; c < 512; c += 256) Ms[c] = Mb[b * 512 + c];
    __syncthreads();
    float acc = 0.f;
    for (int c = 0; c < 512; ++c) acc = fmaf(Ms[c], w1[tid * 512 + c], acc);
    acc += b1[tid];
    float hj = acc > 0.f ? acc : expm1f(acc);   // ELU alpha=1
    float s = blockReduceSum(hj * w2[tid], red);
    if (tid == 0) out[b] = s + b2[0];
}

extern "C" void kernel_launch(void* const* d_in, const int* in_sizes, int n_in,
                              void* d_out, int out_size, void* d_ws, size_t ws_size,
                              hipStream_t stream)
{
    const float* X      = (const float*)d_in[0];
    const float* Wstart = (const float*)d_in[1];
    const float* Bstart = (const float*)d_in[2];
    const float* GluW   = (const float*)d_in[3];
    const float* GluB   = (const float*)d_in[4];
    const float* GcnW   = (const float*)d_in[5];
    const float* GcnB   = (const float*)d_in[6];
    const float* GcnG   = (const float*)d_in[7];
    const float* GcnBe  = (const float*)d_in[8];
    const float* QkvW   = (const float*)d_in[9];
    const float* QkvB   = (const float*)d_in[10];
    const float* OutW   = (const float*)d_in[11];
    const float* OutB   = (const float*)d_in[12];
    const float* Ln1G   = (const float*)d_in[13];
    const float* Ln1B   = (const float*)d_in[14];
    const float* Ffn1W  = (const float*)d_in[15];
    const float* Ffn1B  = (const float*)d_in[16];
    const float* Ffn2W  = (const float*)d_in[17];
    const float* Ffn2B  = (const float*)d_in[18];
    const float* Ln2G   = (const float*)d_in[19];
    const float* Ln2B   = (const float*)d_in[20];
    const float* FusW   = (const float*)d_in[21];
    const float* FusB   = (const float*)d_in[22];
    const float* AW1    = (const float*)d_in[23];
    const float* AB1    = (const float*)d_in[24];
    const float* AW2    = (const float*)d_in[25];
    const float* AB2    = (const float*)d_in[26];
    const float* CW1    = (const float*)d_in[27];
    const float* CB1    = (const float*)d_in[28];
    const float* CW2    = (const float*)d_in[29];
    const float* CB2    = (const float*)d_in[30];
    float* out = (float*)d_out;

    if (ws_size < 86 * MB) return;

    char* w = (char*)d_ws;
    // bf16 weight arena [0,13MB)
    short* Wb = (short*)w;
    short* wbStart = Wb;
    short* wbGlu   = Wb + 524288;
    short* wbGcn   = Wb + 1048576;
    short* wbQkv   = Wb + 1572864;
    short* wbOut   = Wb + 3145728;
    short* wbFfn1  = Wb + 3670016;
    short* wbFfn2  = Wb + 4718592;
    short* wbFus   = Wb + 5767168;
    short* wbAw1   = Wb + 6291456;
    // small [13MB,14MB)
    float* sq   = (float*)(w + 13 * MB);
    int*   idx  = (int*)  (w + 13 * MB + (16u << 10));
    float* srow = (float*)(w + 13 * MB + (176u << 10));
    float* afb  = (float*)(w + 13 * MB + (192u << 10));
    float* Mbuf = (float*)(w + 13 * MB + (208u << 10));
    float* part = (float*)(w + 13 * MB + (212u << 10));
    float* Ml   = (float*)(w + 13 * MB + (384u << 10));   // 512KB
    // overlapped big buffers
    short* Xbf  = (short*)(w + 14 * MB);   // 8MB -> hg after fc_start
    float* hg   = (float*)(w + 14 * MB);
    short* hpreb= (short*)(w + 22 * MB);   // 4MB -> hgb after GLU gemm
    short* hgb  = (short*)(w + 22 * MB);
    float* big  = (float*)(w + 26 * MB);   // 26..42MB: vg/D2/gcn-s/Op/out-proj
    float* ffn2o= (float*)(w + 42 * MB);   // 8MB
    float* h    = (float*)(w + 50 * MB);   // 8MB; doubles as ht residual
    short* hhi  = (short*)(w + 58 * MB);   // 4MB; -> hf low half after loop
    short* hlo  = (short*)(w + 62 * MB);   // 4MB; dead after gram -> htb
    short* htb  = (short*)(w + 62 * MB);   // 4MB (transformer bf16 state)
    float* hf   = (float*)(w + 58 * MB);   // 8MB (after transformer loop)
    short* Vt   = (short*)(w + 66 * MB);   // 4MB; -> hfb after loop
    short* hfb  = (short*)(w + 66 * MB);
    short* aob  = (short*)(w + 70 * MB);   // 4MB; -> t256 (pool)
    float* t256 = (float*)(w + 70 * MB);
    short* Qb   = (short*)(w + 74 * MB);   // 4MB  (OUTMODE=3: K=Qb+4MB, V=Qb+8MB)
    short* Kb   = (short*)(w + 78 * MB);   // 4MB
    short* Vtmp = (short*)(w + 82 * MB);   // 4MB
    short* ffb  = (short*)(w + 74 * MB);   // 8MB (ffn1 out; Qb/Kb dead) -> catb
    short* catb = (short*)(w + 74 * MB);

    dim3 blk(256);

    // convert X + all GEMM weights to bf16
    CvtArgs ca;
    ca.src[0] = X;     ca.dst[0] = Xbf;     ca.n4[0] = ROWS * 1024 / 4;
    ca.src[1] = Wstart;ca.dst[1] = wbStart; ca.n4[1] = 524288 / 4;
    ca.src[2] = GluW;  ca.dst[2] = wbGlu;   ca.n4[2] = 524288 / 4;
    ca.src[3] = GcnW;  ca.dst[3] = wbGcn;   ca.n4[3] = 524288 / 4;
    ca.src[4] = QkvW;  ca.dst[4] = wbQkv;   ca.n4[4] = 1572864 / 4;
    ca.src[5] = OutW;  ca.dst[5] = wbOut;   ca.n4[5] = 524288 / 4;
    ca.src[6] = Ffn1W; ca.dst[6] = wbFfn1;  ca.n4[6] = 1048576 / 4;
    ca.src[7] = Ffn2W; ca.dst[7] = wbFfn2;  ca.n4[7] = 1048576 / 4;
    ca.src[8] = FusW;  ca.dst[8] = wbFus;   ca.n4[8] = 524288 / 4;
    ca.src[9] = AW1;   ca.dst[9] = wbAw1;   ca.n4[9] = 131072 / 4;
    cvt_k<<<dim3(256, 10), blk, 0, stream>>>(ca);

    // fc_start -> GLU (fused rowsq)
    mfma_gemm<1><<<dim3(8, 64), blk, 0, stream>>>(Xbf, wbStart, Bstart, nullptr, hpreb, ROWS, 512, 1024);
    mfma_gemm<0><<<dim3(16, 64), blk, 0, stream>>>(hpreb, wbGlu, GluB, big, nullptr, ROWS, 1024, 512);
    glu_row_k<<<dim3(ROWS), blk, 0, stream>>>(big, h, hg, hhi, hlo, sq);

    // KNN graph (hi/lo split gram, f32-equivalent ranking)
    for (int b = 0; b < 2; ++b) {
        mfma_gram<<<dim3(32, 32), blk, 0, stream>>>(hhi + (size_t)b * NSEQ * 512,
                                                    hlo + (size_t)b * NSEQ * 512,
                                                    sq + b * NSEQ, big);
        topk9_k<<<dim3(NSEQ), blk, 0, stream>>>(big, idx + b * NSEQ * KNN);
    }

    // GCN branch
    const short* gA = hhi;
    for (int i = 0; i < 2; ++i) {
        mfma_gemm<0><<<dim3(8, 64), blk, 0, stream>>>(gA, wbGcn + (size_t)i * 262144,
                                                      GcnB + i * 512, big, nullptr, ROWS, 512, 512);
        gcn_post<<<dim3(ROWS), blk, 0, stream>>>(big, idx, GcnG + i * 512, GcnBe + i * 512, hg, hgb);
        gA = hgb;
    }

    // Transformer branch (h doubles as ht residual)
    const short* tA = hhi;
    for (int i = 0; i < 2; ++i) {
        mfma_gemm<3><<<dim3(24, 64), blk, 0, stream>>>(tA, wbQkv + (size_t)i * 786432,
                                                       QkvB + i * 1536, nullptr, Qb, ROWS, 1536, 512);
        vtr_k<<<dim3(32, 16), blk, 0, stream>>>(Vtmp, Vt);
        flash_attn<<<dim3(32, 2, 16), blk, 0, stream>>>(Qb, Kb, Vt, big, Ml);
        merge_k<<<dim3(8192), blk, 0, stream>>>(big, Ml, aob);
        mfma_gemm<0><<<dim3(8, 64), blk, 0, stream>>>(aob, wbOut + (size_t)i * 262144,
                                                      OutB + i * 512, big, nullptr, ROWS, 512, 512);
        ln_res<<<dim3(ROWS), blk, 0, stream>>>(h, big, Ln1G + i * 512, Ln1B + i * 512, htb);
        mfma_gemm<4><<<dim3(16, 64), blk, 0, stream>>>(htb, wbFfn1 + (size_t)i * 524288,
                                                       Ffn1B + i * 1024, nullptr, ffb, ROWS, 1024, 512);
        mfma_gemm<0><<<dim3(8, 64), blk, 0, stream>>>(ffb, wbFfn2 + (size_t)i * 524288,
                                                      Ffn2B + i * 512, ffn2o, nullptr, ROWS, 512, 1024);
        ln_res<<<dim3(ROWS), blk, 0, stream>>>(h, ffn2o, Ln2G + i * 512, Ln2B + i * 512, htb);
        tA = htb;
    }

    // fusion
    concat_bf<<<dim3(2048), blk, 0, stream>>>(hgb, htb, catb);
    mfma_gemm<2><<<dim3(8, 64), blk, 0, stream>>>(catb, wbFus, FusB, hf, hfb, ROWS, 512, 1024);

    // gated attention pooling (tanh fused into GEMM)
    mfma_gemm<5><<<dim3(4, 64), blk, 0, stream>>>(hfb, wbAw1, AB1, t256, nullptr, ROWS, 256, 512);
    rowdot_k<<<dim3(ROWS), blk, 0, stream>>>(t256, AW2, AB2, srow);
    softmax_n_k<<<dim3(2), blk, 0, stream>>>(srow, afb, out);
    pool_part<<<dim3(32, 2), blk, 0, stream>>>(hf, afb, part);
    pool_fin<<<dim3(2), blk, 0, stream>>>(part, Mbuf, out);

    // classifier
    classifier_k<<<dim3(2), blk, 0, stream>>>(Mbuf, CW1, CB1, CW2, CB2, out);
}